// Round 7
// baseline (1288.959 us; speedup 1.0000x reference)
//
#include <hip/hip_runtime.h>
#include <stdint.h>

typedef __attribute__((ext_vector_type(8))) short bf16x8;
typedef __attribute__((ext_vector_type(4))) float f32x4;
typedef __attribute__((ext_vector_type(4))) unsigned int u32x4;
typedef __attribute__((ext_vector_type(2))) unsigned int u32x2;

#define MFMA(a, b, c) __builtin_amdgcn_mfma_f32_16x16x32_bf16(a, b, c, 0, 0, 0)

__device__ __forceinline__ unsigned short f2b(float x) {
  unsigned u = __float_as_uint(x);
  return (unsigned short)((u + 0x7fffu + ((u >> 16) & 1u)) >> 16);
}
__device__ __forceinline__ float b2f(unsigned short h) {
  return __uint_as_float(((unsigned)h) << 16);
}

// truncation-based Dekker split of two fp32 into packed bf16 hi/lo dwords
struct u2 { unsigned hi, lo; };
__device__ __forceinline__ u2 split2(float h0, float h1) {
  unsigned u0 = __float_as_uint(h0), u1 = __float_as_uint(h1);
  u2 r;
  r.hi = (u0 >> 16) | (u1 & 0xffff0000u);
  float r0 = h0 - __uint_as_float(u0 & 0xffff0000u);
  float r1 = h1 - __uint_as_float(u1 & 0xffff0000u);
  r.lo = (__float_as_uint(r0) >> 16) | (__float_as_uint(r1) & 0xffff0000u);
  return r;
}

// scratch swizzle (used by k_pass2m only)
#define SWZ(row, col) ((col) ^ ((((row) >> 2) & 1) << 4) ^ ((((row) >> 3) & 1) << 2))

// ---------------- setup kernels ----------------

__global__ void k_prep(const float* __restrict__ pa, const float* __restrict__ g0,
                       const float* __restrict__ b0, const float* __restrict__ W1,
                       const float* __restrict__ b1,
                       float* __restrict__ c_pa, float* __restrict__ w_t,
                       float* __restrict__ c_g, float* __restrict__ c_const,
                       float* __restrict__ scal, float* __restrict__ wzT,
                       float* __restrict__ wzZ) {
  int j = threadIdx.x;  // 256 threads, one per W1 row
  const float* wr = W1 + j * 97;
  float cg = 0.f, cc = 0.f, cp = 0.f;
  for (int k = 0; k < 97; ++k) { float w = wr[k]; cg += w * g0[k]; cc += w * b0[k]; }
  for (int k = 0; k < 32; ++k) cp += wr[k] * g0[k] * pa[k];
  c_g[j] = cg;
  c_const[j] = cc + b1[j];
  c_pa[j] = cp;
  w_t[j] = wr[32] * g0[32];
  for (int z = 0; z < 64; ++z) {
    float v = wr[33 + z] * g0[33 + z];
    wzT[j * 64 + z] = v;     // [k][z]
    wzZ[z * 256 + j] = v;    // [z][k]
  }
  if (j == 0) {
    float s = 0.f, q = 0.f;
    for (int k = 0; k < 32; ++k) { float x = pa[k]; s += x; q += x * x; }
    scal[0] = s; scal[1] = q;
  }
}

// st[0..383]: per-z tables; st[384..385]: scal; st[386..399]: Gram terms
__global__ void k_prep2(const float* __restrict__ c_pa, const float* __restrict__ w_t,
                        const float* __restrict__ c_g, const float* __restrict__ c_const,
                        const float* __restrict__ wzT, float* __restrict__ st) {
  int tid = threadIdx.x;  // 128
  if (tid < 64) {
    int z = tid;
    float A = 0.f, Q = 0.f, dpa = 0.f, dwt = 0.f, dcg = 0.f, dcc = 0.f;
    for (int k = 0; k < 256; ++k) {
      float wz = wzT[k * 64 + z];
      A += wz; Q = fmaf(wz, wz, Q);
      dpa = fmaf(c_pa[k], wz, dpa);
      dwt = fmaf(w_t[k], wz, dwt);
      dcg = fmaf(c_g[k], wz, dcg);
      dcc = fmaf(c_const[k], wz, dcc);
    }
    st[z] = A; st[64 + z] = Q; st[128 + z] = dpa;
    st[192 + z] = dwt; st[256 + z] = dcg; st[320 + z] = dcc;
  } else {
    int lane = tid - 64;  // wave 1
    float acc[14];
    #pragma unroll
    for (int m = 0; m < 14; ++m) acc[m] = 0.f;
    for (int k = lane; k < 256; k += 64) {
      float P = c_pa[k], W = w_t[k], G = c_g[k], C = c_const[k];
      acc[0] += P; acc[1] += W; acc[2] += G; acc[3] += C;
      acc[4] = fmaf(P, P, acc[4]); acc[5] = fmaf(P, W, acc[5]);
      acc[6] = fmaf(P, G, acc[6]); acc[7] = fmaf(P, C, acc[7]);
      acc[8] = fmaf(W, W, acc[8]); acc[9] = fmaf(W, G, acc[9]);
      acc[10] = fmaf(W, C, acc[10]); acc[11] = fmaf(G, G, acc[11]);
      acc[12] = fmaf(G, C, acc[12]); acc[13] = fmaf(C, C, acc[13]);
    }
    #pragma unroll
    for (int off = 1; off < 64; off <<= 1) {
      #pragma unroll
      for (int m = 0; m < 14; ++m) acc[m] += __shfl_xor(acc[m], off, 64);
    }
    if (lane == 0) {
      #pragma unroll
      for (int m = 0; m < 14; ++m) st[386 + m] = acc[m];
    }
  }
}

__global__ void k_scal2st(const float* __restrict__ scal, float* __restrict__ st) {
  if (threadIdx.x < 2) st[384 + threadIdx.x] = scal[threadIdx.x];
}

__global__ void k_adj(const int* __restrict__ ei, unsigned long long* __restrict__ adj) {
  int t = threadIdx.x;  // 256
  if (t < 64) adj[t] = 1ull << t;
  __syncthreads();
  int u = ei[t] & 63, v = ei[256 + t] & 63;
  atomicOr(&adj[u], 1ull << v);
  atomicOr(&adj[v], 1ull << u);
}

// Pre-split weights into MFMA A-fragment order, bf16 hi/lo (RNE, done once).
__global__ void k_wsplit(const float* __restrict__ W2, const float* __restrict__ W3,
                         const float* __restrict__ W4,
                         unsigned short* __restrict__ W2Ah, unsigned short* __restrict__ W2Al,
                         unsigned short* __restrict__ W3Ah, unsigned short* __restrict__ W3Al,
                         unsigned short* __restrict__ W4Ah, unsigned short* __restrict__ W4Al) {
  int idx = blockIdx.x * 256 + threadIdx.x;
  float w; unsigned short* ph; unsigned short* pl; int o;
  if (idx < 32768) {                       // W2 [128][256]
    int mt = idx >> 12, kt = (idx >> 9) & 7, lane = (idx >> 3) & 63, j = idx & 7;
    int m = mt * 16 + (lane & 15), k = kt * 32 + (lane >> 4) * 8 + j;
    w = W2[m * 256 + k]; ph = W2Ah; pl = W2Al; o = idx;
  } else if (idx < 40960) {                // W3 [64][128]
    int r = idx - 32768;
    int mt = r >> 11, kt = (r >> 9) & 3, lane = (r >> 3) & 63, j = r & 7;
    int m = mt * 16 + (lane & 15), k = kt * 32 + (lane >> 4) * 8 + j;
    w = W3[m * 128 + k]; ph = W3Ah; pl = W3Al; o = r;
  } else if (idx < 45056) {                // W4 [64][64]
    int r = idx - 40960;
    int mt = r >> 10, kt = (r >> 9) & 1, lane = (r >> 3) & 63, j = r & 7;
    int m = mt * 16 + (lane & 15), k = kt * 32 + (lane >> 4) * 8 + j;
    w = W4[m * 64 + k]; ph = W4Ah; pl = W4Al; o = r;
  } else return;
  unsigned short hb = f2b(w);
  ph[o] = hb;
  pl[o] = f2b(w - b2f(hb));
}

// ---------------- pass 1: transition table next[i][z] ----------------
// 16KB frag region (K=64 chunks everywhere) -> ~19.5KB LDS -> 8 blocks/CU.
// Direct acc->fragment scatter with shared P/Q LN tables (1 rsqrt per layer).

__global__ __launch_bounds__(256, 8) void k_pass1(
    const float* __restrict__ times,
    const float* __restrict__ c_pa, const float* __restrict__ w_t,
    const float* __restrict__ c_g, const float* __restrict__ c_const,
    const float* __restrict__ wzT, const float* __restrict__ st,
    const unsigned short* __restrict__ W2Ah, const unsigned short* __restrict__ W2Al,
    const unsigned short* __restrict__ W3Ah, const unsigned short* __restrict__ W3Al,
    const unsigned short* __restrict__ W4Ah, const unsigned short* __restrict__ W4Al,
    const float* __restrict__ b2, const float* __restrict__ b3,
    const float* __restrict__ b4,
    const float* __restrict__ g1, const float* __restrict__ be1,
    const float* __restrict__ g2, const float* __restrict__ be2,
    const float* __restrict__ g3, const float* __restrict__ be3,
    const unsigned long long* __restrict__ adj,
    unsigned char* __restrict__ nxt) {
  __shared__ __align__(16) char region[16384];   // [2kt][4nt][64][8] hi | lo
  __shared__ float u_lds[256];
  __shared__ float ps[512];                      // partials; P/Q tables; pk alias

  unsigned short* Bhi = (unsigned short*)region;
  unsigned short* Blo = (unsigned short*)(region + 8192);
  unsigned long long* pk = (unsigned long long*)ps;

  const int tid = threadIdx.x;
  const int lane = tid & 63;          // lane == zone z for producer phases
  const int l15 = lane & 15;
  const int lhi = lane >> 4;
  const int w = __builtin_amdgcn_readfirstlane(tid >> 6);
  const int i = blockIdx.x;

  const float t = times[i];
  const float m0 = (st[384] + t + 1.0f) * (1.0f / 97.0f);
  const float e2 = (st[385] + t * t + 1.0f) * (1.0f / 97.0f);
  const float alpha = 1.0f / sqrtf(e2 - m0 * m0 + 1e-5f);
  const float gma = -m0 * alpha;

  const f32x4 zero4 = {0.f, 0.f, 0.f, 0.f};

  // ---- u(k) once per k + block sums; closed-form LN1 stats per z ----
  {
    int k = tid;
    float u = fmaf(t, w_t[k], c_pa[k]);
    u = fmaf(alpha, u, c_const[k]);
    u = fmaf(gma, c_g[k], u);
    u_lds[k] = u;
    float su = u, sq = u * u;
    #pragma unroll
    for (int off = 1; off < 64; off <<= 1) {
      su += __shfl_xor(su, off, 64);
      sq += __shfl_xor(sq, off, 64);
    }
    if (lane == 0) { ps[w] = su; ps[256 + w] = sq; }
  }
  __syncthreads();
  float mu1, inv1;
  {
    float U1 = ps[0] + ps[1] + ps[2] + ps[3];
    float Qu = ps[256] + ps[257] + ps[258] + ps[259];
    float A1 = st[lane], Qz = st[64 + lane];
    float dpa = st[128 + lane], dwt = st[192 + lane];
    float dcg = st[256 + lane], dcc = st[320 + lane];
    float s1 = fmaf(alpha, A1, U1);
    float uwz = fmaf(alpha, fmaf(t, dwt, dpa), fmaf(gma, dcg, dcc));
    float s2 = Qu + 2.0f * alpha * uwz + alpha * alpha * Qz;
    mu1 = s1 * (1.0f / 256.0f);
    inv1 = 1.0f / sqrtf(s2 * (1.0f / 256.0f) - mu1 * mu1 + 1e-5f);
  }

  // ---- GEMM1: h2[128][64] = W2 @ h1, K=256 in 4 chunks of 64 ----
  f32x4 acc[2][4];
  #pragma unroll
  for (int a = 0; a < 2; ++a)
    #pragma unroll
    for (int b = 0; b < 4; ++b) acc[a][b] = zero4;

  for (int kc = 0; kc < 4; ++kc) {
    if (kc) __syncthreads();          // previous chunk's MFMA readers done
    // producers: 2 octets per wave: o = w*2+q, k = kc*64 + o*8 + j, z = lane
    #pragma unroll
    for (int q = 0; q < 2; ++q) {
      int o = w * 2 + q;
      int kb = kc * 64 + o * 8;
      f32x4 u0 = *(const f32x4*)(u_lds + kb);
      f32x4 u1v = *(const f32x4*)(u_lds + kb + 4);
      float hbuf[8];
      #pragma unroll
      for (int j = 0; j < 8; ++j) {
        int k = kb + j;
        float u = (j < 4) ? u0[j] : u1v[j - 4];
        float p = fmaf(alpha, wzT[k * 64 + lane], u);
        float gi = g1[k] * inv1;
        float bb = fmaf(-mu1, gi, be1[k]);
        hbuf[j] = fmaxf(fmaf(p, gi, bb), 0.f);
      }
      u32x4 vh, vl;
      #pragma unroll
      for (int e = 0; e < 4; ++e) {
        u2 s = split2(hbuf[2 * e], hbuf[2 * e + 1]);
        vh[e] = s.hi; vl[e] = s.lo;
      }
      int slotd = (((o >> 2) * 4 + lhi) * 64 + (o & 3) * 16 + l15) * 4;
      *(u32x4*)((unsigned*)Bhi + slotd) = vh;
      *(u32x4*)((unsigned*)Blo + slotd) = vl;
    }
    __syncthreads();
    // MFMA: wave owns M rows [32w, 32w+32)
    #pragma unroll
    for (int kt = 0; kt < 2; ++kt) {
      int ktg = kc * 2 + kt;
      bf16x8 a0h = *(const bf16x8*)(W2Ah + (((2 * w + 0) * 8 + ktg) * 64 + lane) * 8);
      bf16x8 a0l = *(const bf16x8*)(W2Al + (((2 * w + 0) * 8 + ktg) * 64 + lane) * 8);
      bf16x8 a1h = *(const bf16x8*)(W2Ah + (((2 * w + 1) * 8 + ktg) * 64 + lane) * 8);
      bf16x8 a1l = *(const bf16x8*)(W2Al + (((2 * w + 1) * 8 + ktg) * 64 + lane) * 8);
      #pragma unroll
      for (int nt = 0; nt < 4; ++nt) {
        bf16x8 bh = *(const bf16x8*)(Bhi + ((kt * 4 + nt) * 64 + lane) * 8);
        bf16x8 bl = *(const bf16x8*)(Blo + ((kt * 4 + nt) * 64 + lane) * 8);
        acc[0][nt] = MFMA(a0h, bh, acc[0][nt]);
        acc[0][nt] = MFMA(a0h, bl, acc[0][nt]);
        acc[0][nt] = MFMA(a0l, bh, acc[0][nt]);
        acc[1][nt] = MFMA(a1h, bh, acc[1][nt]);
        acc[1][nt] = MFMA(a1h, bl, acc[1][nt]);
        acc[1][nt] = MFMA(a1l, bh, acc[1][nt]);
      }
    }
  }

  // +b2, LN2 partial sums (per column over 128 rows)
  #pragma unroll
  for (int mti = 0; mti < 2; ++mti) {
    f32x4 bv = *(const f32x4*)(b2 + w * 32 + mti * 16 + lhi * 4);
    #pragma unroll
    for (int nt = 0; nt < 4; ++nt) acc[mti][nt] += bv;
  }
  #pragma unroll
  for (int nt = 0; nt < 4; ++nt) {
    float x1 = 0.f, x2 = 0.f;
    #pragma unroll
    for (int mti = 0; mti < 2; ++mti)
      #pragma unroll
      for (int r = 0; r < 4; ++r) { float v = acc[mti][nt][r]; x1 += v; x2 += v * v; }
    x1 += __shfl_xor(x1, 16, 64); x1 += __shfl_xor(x1, 32, 64);
    x2 += __shfl_xor(x2, 16, 64); x2 += __shfl_xor(x2, 32, 64);
    if (lane < 16) {
      ps[w * 64 + nt * 16 + lane] = x1;
      ps[256 + w * 64 + nt * 16 + lane] = x2;
    }
  }
  __syncthreads();
  // P/Q table for LN2 (wave 0 only; one rsqrt per column)
  if (w == 0) {
    int c = lane;
    float a = ps[c] + ps[64 + c] + ps[128 + c] + ps[192 + c];
    float b = ps[256 + c] + ps[320 + c] + ps[384 + c] + ps[448 + c];
    float mu = a * (1.0f / 128.0f);
    float inv = 1.0f / sqrtf(b * (1.0f / 128.0f) - mu * mu + 1e-5f);
    ps[c] = inv;               // P
    ps[64 + c] = -mu * inv;    // Q
  }
  __syncthreads();

  // ---- GEMM2: h3[64][64] = W3 @ h2, K=128 in 2 chunks of 64 ----
  f32x4 acc2[4];
  #pragma unroll
  for (int b = 0; b < 4; ++b) acc2[b] = zero4;

  for (int kc2 = 0; kc2 < 2; ++kc2) {
    if ((w >> 1) == kc2) {            // waves 2*kc2, 2*kc2+1 own these h2 rows
      f32x4 g2v[2], be2v[2];
      #pragma unroll
      for (int mti = 0; mti < 2; ++mti) {
        g2v[mti]  = *(const f32x4*)(g2  + w * 32 + mti * 16 + lhi * 4);
        be2v[mti] = *(const f32x4*)(be2 + w * 32 + mti * 16 + lhi * 4);
      }
      #pragma unroll
      for (int nt = 0; nt < 4; ++nt) {
        int c = nt * 16 + l15;
        float P = ps[c], Q = ps[64 + c];
        #pragma unroll
        for (int mti = 0; mti < 2; ++mti) {
          float h[4];
          #pragma unroll
          for (int r = 0; r < 4; ++r) {
            float G = g2v[mti][r];
            h[r] = fmaxf(fmaf(acc[mti][nt][r], G * P, fmaf(G, Q, be2v[mti][r])), 0.f);
          }
          u2 s01 = split2(h[0], h[1]);
          u2 s23 = split2(h[2], h[3]);
          int base = (((w - 2 * kc2) * 4 + nt) * 64 +
                      (mti * 2 + (lhi >> 1)) * 16 + l15) * 8 + (lhi & 1) * 4;
          u32x2 vh = {s01.hi, s23.hi};
          u32x2 vl = {s01.lo, s23.lo};
          *(u32x2*)(Bhi + base) = vh;
          *(u32x2*)(Blo + base) = vl;
        }
      }
    }
    __syncthreads();
    #pragma unroll
    for (int kt = 0; kt < 2; ++kt) {
      int ktg = kc2 * 2 + kt;
      bf16x8 ah = *(const bf16x8*)(W3Ah + ((w * 4 + ktg) * 64 + lane) * 8);
      bf16x8 al = *(const bf16x8*)(W3Al + ((w * 4 + ktg) * 64 + lane) * 8);
      #pragma unroll
      for (int nt = 0; nt < 4; ++nt) {
        bf16x8 bh = *(const bf16x8*)(Bhi + ((kt * 4 + nt) * 64 + lane) * 8);
        bf16x8 bl = *(const bf16x8*)(Blo + ((kt * 4 + nt) * 64 + lane) * 8);
        acc2[nt] = MFMA(ah, bh, acc2[nt]);
        acc2[nt] = MFMA(ah, bl, acc2[nt]);
        acc2[nt] = MFMA(al, bh, acc2[nt]);
      }
    }
    __syncthreads();
  }

  // +b3, LN3 partial sums
  {
    f32x4 bv = *(const f32x4*)(b3 + w * 16 + lhi * 4);
    #pragma unroll
    for (int nt = 0; nt < 4; ++nt) acc2[nt] += bv;
  }
  #pragma unroll
  for (int nt = 0; nt < 4; ++nt) {
    float x1 = 0.f, x2 = 0.f;
    #pragma unroll
    for (int r = 0; r < 4; ++r) { float v = acc2[nt][r]; x1 += v; x2 += v * v; }
    x1 += __shfl_xor(x1, 16, 64); x1 += __shfl_xor(x1, 32, 64);
    x2 += __shfl_xor(x2, 16, 64); x2 += __shfl_xor(x2, 32, 64);
    if (lane < 16) {
      ps[w * 64 + nt * 16 + lane] = x1;
      ps[256 + w * 64 + nt * 16 + lane] = x2;
    }
  }
  __syncthreads();
  if (w == 0) {
    int c = lane;
    float a = ps[c] + ps[64 + c] + ps[128 + c] + ps[192 + c];
    float b = ps[256 + c] + ps[320 + c] + ps[384 + c] + ps[448 + c];
    float mu = a * (1.0f / 64.0f);
    float inv = 1.0f / sqrtf(b * (1.0f / 64.0f) - mu * mu + 1e-5f);
    ps[c] = inv;               // P
    ps[64 + c] = -mu * inv;    // Q
  }
  __syncthreads();

  // ---- B3 producers: all waves, direct scatter from acc2 ----
  {
    f32x4 g3v  = *(const f32x4*)(g3  + w * 16 + lhi * 4);
    f32x4 be3v = *(const f32x4*)(be3 + w * 16 + lhi * 4);
    #pragma unroll
    for (int nt = 0; nt < 4; ++nt) {
      int c = nt * 16 + l15;
      float P = ps[c], Q = ps[64 + c];
      float h[4];
      #pragma unroll
      for (int r = 0; r < 4; ++r) {
        float G = g3v[r];
        h[r] = fmaxf(fmaf(acc2[nt][r], G * P, fmaf(G, Q, be3v[r])), 0.f);
      }
      u2 s01 = split2(h[0], h[1]);
      u2 s23 = split2(h[2], h[3]);
      int base = (((w >> 1) * 4 + nt) * 64 +
                  ((w & 1) * 2 + (lhi >> 1)) * 16 + l15) * 8 + (lhi & 1) * 4;
      u32x2 vh = {s01.hi, s23.hi};
      u32x2 vl = {s01.lo, s23.lo};
      *(u32x2*)(Bhi + base) = vh;
      *(u32x2*)(Blo + base) = vl;
    }
  }
  __syncthreads();

  // ---- GEMM3: raw[64][64] = W4 @ h3 ----
  f32x4 acc3[4];
  #pragma unroll
  for (int b = 0; b < 4; ++b) acc3[b] = zero4;
  #pragma unroll
  for (int kt = 0; kt < 2; ++kt) {
    bf16x8 ah = *(const bf16x8*)(W4Ah + ((w * 2 + kt) * 64 + lane) * 8);
    bf16x8 al = *(const bf16x8*)(W4Al + ((w * 2 + kt) * 64 + lane) * 8);
    #pragma unroll
    for (int nt = 0; nt < 4; ++nt) {
      bf16x8 bh = *(const bf16x8*)(Bhi + ((kt * 4 + nt) * 64 + lane) * 8);
      bf16x8 bl = *(const bf16x8*)(Blo + ((kt * 4 + nt) * 64 + lane) * 8);
      acc3[nt] = MFMA(ah, bh, acc3[nt]);
      acc3[nt] = MFMA(ah, bl, acc3[nt]);
      acc3[nt] = MFMA(al, bh, acc3[nt]);
    }
  }
  f32x4 b4v = *(const f32x4*)(b4 + w * 16 + lhi * 4);
  unsigned long long kbest[4];
  #pragma unroll
  for (int nt = 0; nt < 4; ++nt) {
    unsigned long long am = adj[nt * 16 + l15];
    unsigned long long kb = 0ull;
    #pragma unroll
    for (int r = 0; r < 4; ++r) {
      int o = w * 16 + lhi * 4 + r;
      float raw = acc3[nt][r] + b4v[r];
      float val = ((am >> o) & 1ull) ? raw : -__builtin_huge_valf();
      unsigned u = __float_as_uint(val);
      u = (u & 0x80000000u) ? ~u : (u | 0x80000000u);
      unsigned long long key = ((unsigned long long)u << 6) | (unsigned long long)(63 - o);
      if (key > kb) kb = key;
    }
    unsigned long long oth = __shfl_xor(kb, 16, 64); if (oth > kb) kb = oth;
    oth = __shfl_xor(kb, 32, 64); if (oth > kb) kb = oth;
    kbest[nt] = kb;
  }
  if (lane < 16) {
    #pragma unroll
    for (int nt = 0; nt < 4; ++nt) pk[w * 64 + nt * 16 + lane] = kbest[nt];
  }
  __syncthreads();
  if (tid < 64) {
    unsigned long long k0 = pk[tid], k1 = pk[64 + tid];
    unsigned long long k2 = pk[128 + tid], k3 = pk[192 + tid];
    unsigned long long a = k0 > k1 ? k0 : k1;
    unsigned long long b = k2 > k3 ? k2 : k3;
    unsigned long long bb = a > b ? a : b;
    nxt[(size_t)i * 64 + tid] = (unsigned char)(63u - (unsigned)(bb & 63ull));
  }
}

// ---------------- trajectory via parallel map-composition scan ----------------

__global__ void k_scan_a(const unsigned char* __restrict__ nxt,
                         unsigned char* __restrict__ cmap) {
  int c = blockIdx.x, lane = threadIdx.x;
  int g = lane;
  const unsigned char* p = nxt + (size_t)c * 128 * 64;
  for (int s = 0; s < 128; ++s) {
    int sig = p[s * 64 + lane];
    g = __shfl(sig, g, 64);
  }
  cmap[c * 64 + lane] = (unsigned char)g;
}

__global__ void k_scan_b(const unsigned char* __restrict__ cmap,
                         int* __restrict__ startz) {
  int lane = threadIdx.x;
  int cur = 0;
  for (int c = 0; c < 256; ++c) {
    if (lane == 0) startz[c] = cur;
    int row = cmap[c * 64 + lane];
    cur = __shfl(row, cur, 64);
  }
}

__global__ void k_scan_c(const unsigned char* __restrict__ nxt,
                         const int* __restrict__ startz,
                         unsigned char* __restrict__ zones) {
  int c = blockIdx.x, lane = threadIdx.x;
  int cur = startz[c];
  const unsigned char* p = nxt + (size_t)c * 128 * 64;
  for (int s = 0; s < 128; ++s) {
    if (lane == 0) zones[c * 128 + s] = (unsigned char)cur;
    int row = p[s * 64 + lane];
    cur = __shfl(row, cur, 64);
  }
}

// ---------------- pass 2m: logits for actual zones, 64 timesteps/block ----------------

__global__ __launch_bounds__(256, 2) void k_pass2m(
    const float* __restrict__ times, const unsigned char* __restrict__ zones,
    const float* __restrict__ c_pa, const float* __restrict__ w_t,
    const float* __restrict__ c_g, const float* __restrict__ c_const,
    const float* __restrict__ wzZ, const float* __restrict__ st,
    const unsigned short* __restrict__ W2Ah, const unsigned short* __restrict__ W2Al,
    const unsigned short* __restrict__ W3Ah, const unsigned short* __restrict__ W3Al,
    const unsigned short* __restrict__ W4Ah, const unsigned short* __restrict__ W4Al,
    const float* __restrict__ b2, const float* __restrict__ b3,
    const float* __restrict__ b4,
    const float* __restrict__ g1, const float* __restrict__ be1,
    const float* __restrict__ g2, const float* __restrict__ be2,
    const float* __restrict__ g3, const float* __restrict__ be3,
    const unsigned long long* __restrict__ adj,
    float* __restrict__ out) {
  __shared__ __align__(16) char region[32768];
  __shared__ float ps1[256], ps2[256];
  __shared__ unsigned long long am_lds[64];

  unsigned short* B1hi = (unsigned short*)region;
  unsigned short* B1lo = (unsigned short*)(region + 16384);
  float* h2p = (float*)region;
  unsigned short* B2hi = (unsigned short*)region;
  unsigned short* B2lo = (unsigned short*)(region + 16384);
  float* h3p = (float*)region;
  unsigned short* B3hi = (unsigned short*)(region + 16384);
  unsigned short* B3lo = (unsigned short*)(region + 24576);
  float* outT = (float*)region;

  const int tid = threadIdx.x;
  const int lane = tid & 63;
  const int l15 = lane & 15;
  const int lhi = lane >> 4;
  const int w = __builtin_amdgcn_readfirstlane(tid >> 6);
  const int i0 = blockIdx.x * 64;

  const float t = times[i0 + lane];
  const int z = zones[i0 + lane];
  const int zrow = z << 8;
  if (tid < 64) am_lds[tid] = adj[zones[i0 + tid]];

  const float m0 = (st[384] + t + 1.0f) * (1.0f / 97.0f);
  const float e2 = (st[385] + t * t + 1.0f) * (1.0f / 97.0f);
  const float a0 = 1.0f / sqrtf(e2 - m0 * m0 + 1e-5f);
  const float a1 = a0 * t;
  const float a2 = -m0 * a0;

  float mu1, inv1;
  {
    float SP = st[386], SW = st[387], SG = st[388], SC = st[389];
    float PP = st[390], PW = st[391], PG = st[392], PC = st[393];
    float WW = st[394], WG = st[395], WC = st[396];
    float GG = st[397], GC = st[398], CC = st[399];
    float U1 = a0 * SP + a1 * SW + a2 * SG + SC;
    float s1 = fmaf(a0, st[z], U1);
    float Qu = a0 * a0 * PP + a1 * a1 * WW + a2 * a2 * GG + CC
             + 2.0f * (a0 * a1 * PW + a0 * a2 * PG + a0 * PC
                       + a1 * a2 * WG + a1 * WC + a2 * GC);
    float uwz = a0 * st[128 + z] + a1 * st[192 + z] + a2 * st[256 + z] + st[320 + z];
    float s2 = Qu + 2.0f * a0 * uwz + a0 * a0 * st[64 + z];
    mu1 = s1 * (1.0f / 256.0f);
    inv1 = 1.0f / sqrtf(s2 * (1.0f / 256.0f) - mu1 * mu1 + 1e-5f);
  }

  const f32x4 zero4 = {0.f, 0.f, 0.f, 0.f};
  f32x4 acc[2][4];
  #pragma unroll
  for (int a = 0; a < 2; ++a)
    #pragma unroll
    for (int b = 0; b < 4; ++b) acc[a][b] = zero4;

  for (int kc = 0; kc < 2; ++kc) {
    if (kc) __syncthreads();
    #pragma unroll
    for (int q = 0; q < 4; ++q) {
      int kb = kc * 128 + w * 32 + q * 8;
      float hbuf[8];
      #pragma unroll
      for (int j = 0; j < 8; ++j) {
        int k = kb + j;
        float u = fmaf(a0, c_pa[k], fmaf(a1, w_t[k], fmaf(a2, c_g[k], c_const[k])));
        float p = fmaf(a0, wzZ[zrow + k], u);
        float gi = g1[k] * inv1;
        float bb = fmaf(-mu1, gi, be1[k]);
        hbuf[j] = fmaxf(fmaf(p, gi, bb), 0.f);
      }
      u32x4 vh, vl;
      #pragma unroll
      for (int e = 0; e < 4; ++e) {
        u2 s = split2(hbuf[2 * e], hbuf[2 * e + 1]);
        vh[e] = s.hi; vl[e] = s.lo;
      }
      int slotd = ((w * 4 + lhi) * 64 + q * 16 + l15) * 4;
      *(u32x4*)((unsigned*)B1hi + slotd) = vh;
      *(u32x4*)((unsigned*)B1lo + slotd) = vl;
    }
    __syncthreads();
    for (int kt = 0; kt < 4; ++kt) {
      int ktg = kc * 4 + kt;
      bf16x8 a0h = *(const bf16x8*)(W2Ah + (((2 * w + 0) * 8 + ktg) * 64 + lane) * 8);
      bf16x8 a0l = *(const bf16x8*)(W2Al + (((2 * w + 0) * 8 + ktg) * 64 + lane) * 8);
      bf16x8 a1h = *(const bf16x8*)(W2Ah + (((2 * w + 1) * 8 + ktg) * 64 + lane) * 8);
      bf16x8 a1l = *(const bf16x8*)(W2Al + (((2 * w + 1) * 8 + ktg) * 64 + lane) * 8);
      #pragma unroll
      for (int nt = 0; nt < 4; ++nt) {
        bf16x8 bh = *(const bf16x8*)(B1hi + ((kt * 4 + nt) * 64 + lane) * 8);
        bf16x8 bl = *(const bf16x8*)(B1lo + ((kt * 4 + nt) * 64 + lane) * 8);
        acc[0][nt] = MFMA(a0h, bh, acc[0][nt]);
        acc[0][nt] = MFMA(a0h, bl, acc[0][nt]);
        acc[0][nt] = MFMA(a0l, bh, acc[0][nt]);
        acc[1][nt] = MFMA(a1h, bh, acc[1][nt]);
        acc[1][nt] = MFMA(a1h, bl, acc[1][nt]);
        acc[1][nt] = MFMA(a1l, bh, acc[1][nt]);
      }
    }
  }
  #pragma unroll
  for (int mti = 0; mti < 2; ++mti) {
    f32x4 bv = *(const f32x4*)(b2 + w * 32 + mti * 16 + lhi * 4);
    #pragma unroll
    for (int nt = 0; nt < 4; ++nt) acc[mti][nt] += bv;
  }
  {
    float sa[4], sb[4];
    #pragma unroll
    for (int nt = 0; nt < 4; ++nt) {
      float x1 = 0.f, x2 = 0.f;
      #pragma unroll
      for (int mti = 0; mti < 2; ++mti)
        #pragma unroll
        for (int r = 0; r < 4; ++r) { float v = acc[mti][nt][r]; x1 += v; x2 += v * v; }
      x1 += __shfl_xor(x1, 16, 64); x1 += __shfl_xor(x1, 32, 64);
      x2 += __shfl_xor(x2, 16, 64); x2 += __shfl_xor(x2, 32, 64);
      sa[nt] = x1; sb[nt] = x2;
    }
    if (lane < 16) {
      #pragma unroll
      for (int nt = 0; nt < 4; ++nt) {
        ps1[w * 64 + nt * 16 + lane] = sa[nt];
        ps2[w * 64 + nt * 16 + lane] = sb[nt];
      }
    }
  }
  __syncthreads();
  #pragma unroll
  for (int mti = 0; mti < 2; ++mti)
    #pragma unroll
    for (int nt = 0; nt < 4; ++nt)
      #pragma unroll
      for (int r = 0; r < 4; ++r) {
        int row = w * 32 + mti * 16 + lhi * 4 + r;
        h2p[row * 64 + SWZ(row, nt * 16 + l15)] = acc[mti][nt][r];
      }
  __syncthreads();

  float mu2, inv2;
  {
    float a = ps1[lane] + ps1[64 + lane] + ps1[128 + lane] + ps1[192 + lane];
    float b = ps2[lane] + ps2[64 + lane] + ps2[128 + lane] + ps2[192 + lane];
    mu2 = a * (1.0f / 128.0f);
    inv2 = 1.0f / sqrtf(b * (1.0f / 128.0f) - mu2 * mu2 + 1e-5f);
  }
  float hv[32];
  #pragma unroll
  for (int mi = 0; mi < 32; ++mi) {
    int row = w * 32 + mi;
    hv[mi] = h2p[row * 64 + SWZ(row, lane)];
  }
  __syncthreads();
  #pragma unroll
  for (int q = 0; q < 4; ++q) {
    float hbuf[8];
    #pragma unroll
    for (int j = 0; j < 8; ++j) {
      int mi = q * 8 + j, mm = w * 32 + mi;
      float gi = g2[mm] * inv2;
      float bb = fmaf(-mu2, gi, be2[mm]);
      hbuf[j] = fmaxf(fmaf(hv[mi], gi, bb), 0.f);
    }
    u32x4 vh, vl;
    #pragma unroll
    for (int e = 0; e < 4; ++e) {
      u2 s = split2(hbuf[2 * e], hbuf[2 * e + 1]);
      vh[e] = s.hi; vl[e] = s.lo;
    }
    int slotd = ((w * 4 + lhi) * 64 + q * 16 + l15) * 4;
    *(u32x4*)((unsigned*)B2hi + slotd) = vh;
    *(u32x4*)((unsigned*)B2lo + slotd) = vl;
  }
  __syncthreads();

  f32x4 acc2[4];
  #pragma unroll
  for (int b = 0; b < 4; ++b) acc2[b] = zero4;
  for (int kt = 0; kt < 4; ++kt) {
    bf16x8 ah = *(const bf16x8*)(W3Ah + ((w * 4 + kt) * 64 + lane) * 8);
    bf16x8 al = *(const bf16x8*)(W3Al + ((w * 4 + kt) * 64 + lane) * 8);
    #pragma unroll
    for (int nt = 0; nt < 4; ++nt) {
      bf16x8 bh = *(const bf16x8*)(B2hi + ((kt * 4 + nt) * 64 + lane) * 8);
      bf16x8 bl = *(const bf16x8*)(B2lo + ((kt * 4 + nt) * 64 + lane) * 8);
      acc2[nt] = MFMA(ah, bh, acc2[nt]);
      acc2[nt] = MFMA(ah, bl, acc2[nt]);
      acc2[nt] = MFMA(al, bh, acc2[nt]);
    }
  }
  {
    f32x4 bv = *(const f32x4*)(b3 + w * 16 + lhi * 4);
    #pragma unroll
    for (int nt = 0; nt < 4; ++nt) acc2[nt] += bv;
  }
  {
    float sa[4], sb[4];
    #pragma unroll
    for (int nt = 0; nt < 4; ++nt) {
      float x1 = 0.f, x2 = 0.f;
      #pragma unroll
      for (int r = 0; r < 4; ++r) { float v = acc2[nt][r]; x1 += v; x2 += v * v; }
      x1 += __shfl_xor(x1, 16, 64); x1 += __shfl_xor(x1, 32, 64);
      x2 += __shfl_xor(x2, 16, 64); x2 += __shfl_xor(x2, 32, 64);
      sa[nt] = x1; sb[nt] = x2;
    }
    if (lane < 16) {
      #pragma unroll
      for (int nt = 0; nt < 4; ++nt) {
        ps1[w * 64 + nt * 16 + lane] = sa[nt];
        ps2[w * 64 + nt * 16 + lane] = sb[nt];
      }
    }
  }
  __syncthreads();
  #pragma unroll
  for (int nt = 0; nt < 4; ++nt)
    #pragma unroll
    for (int r = 0; r < 4; ++r) {
      int row = w * 16 + lhi * 4 + r;
      h3p[row * 64 + SWZ(row, nt * 16 + l15)] = acc2[nt][r];
    }
  __syncthreads();

  float mu3, inv3;
  {
    float a = ps1[lane] + ps1[64 + lane] + ps1[128 + lane] + ps1[192 + lane];
    float b = ps2[lane] + ps2[64 + lane] + ps2[128 + lane] + ps2[192 + lane];
    mu3 = a * (1.0f / 64.0f);
    inv3 = 1.0f / sqrtf(b * (1.0f / 64.0f) - mu3 * mu3 + 1e-5f);
  }
  #pragma unroll
  for (int q = 0; q < 2; ++q) {
    int o = w * 2 + q;
    float hbuf[8];
    #pragma unroll
    for (int j = 0; j < 8; ++j) {
      int mm = o * 8 + j;
      float v = h3p[mm * 64 + SWZ(mm, lane)];
      float gi = g3[mm] * inv3;
      float bb = fmaf(-mu3, gi, be3[mm]);
      hbuf[j] = fmaxf(fmaf(v, gi, bb), 0.f);
    }
    u32x4 vh, vl;
    #pragma unroll
    for (int e = 0; e < 4; ++e) {
      u2 s = split2(hbuf[2 * e], hbuf[2 * e + 1]);
      vh[e] = s.hi; vl[e] = s.lo;
    }
    int slotd = (((o >> 2) * 4 + lhi) * 64 + (o & 3) * 16 + l15) * 4;
    *(u32x4*)((unsigned*)B3hi + slotd) = vh;
    *(u32x4*)((unsigned*)B3lo + slotd) = vl;
  }
  __syncthreads();

  f32x4 acc3[4];
  #pragma unroll
  for (int b = 0; b < 4; ++b) acc3[b] = zero4;
  for (int kt = 0; kt < 2; ++kt) {
    bf16x8 ah = *(const bf16x8*)(W4Ah + ((w * 2 + kt) * 64 + lane) * 8);
    bf16x8 al = *(const bf16x8*)(W4Al + ((w * 2 + kt) * 64 + lane) * 8);
    #pragma unroll
    for (int nt = 0; nt < 4; ++nt) {
      bf16x8 bh = *(const bf16x8*)(B3hi + ((kt * 4 + nt) * 64 + lane) * 8);
      bf16x8 bl = *(const bf16x8*)(B3lo + ((kt * 4 + nt) * 64 + lane) * 8);
      acc3[nt] = MFMA(ah, bh, acc3[nt]);
      acc3[nt] = MFMA(ah, bl, acc3[nt]);
      acc3[nt] = MFMA(al, bh, acc3[nt]);
    }
  }
  f32x4 b4v = *(const f32x4*)(b4 + w * 16 + lhi * 4);
  #pragma unroll
  for (int nt = 0; nt < 4; ++nt) {
    unsigned long long am = am_lds[nt * 16 + l15];
    #pragma unroll
    for (int r = 0; r < 4; ++r) {
      int o = w * 16 + lhi * 4 + r;
      float raw = acc3[nt][r] + b4v[r];
      float predv = ((am >> o) & 1ull) ? raw : -50.0f;
      int b = nt * 16 + l15;
      outT[b * 64 + SWZ(b, o)] = predv;
    }
  }
  __syncthreads();
  {
    int b = tid >> 2, cb = (tid & 3) * 16;
    size_t gbase = ((size_t)(i0 + b)) * 64 + cb;
    #pragma unroll
    for (int c4 = 0; c4 < 4; ++c4) {
      int col = cb + c4 * 4;
      f32x4 v = *(const f32x4*)(outT + b * 64 + SWZ(b, col));
      *(f32x4*)(out + gbase + c4 * 4) = v;
    }
  }
}

// ---------------- launch ----------------

extern "C" void kernel_launch(void* const* d_in, const int* in_sizes, int n_in,
                              void* d_out, int out_size, void* d_ws, size_t ws_size,
                              hipStream_t stream) {
  const float* pa    = (const float*)d_in[0];
  const float* times = (const float*)d_in[1];
  const int*   ei    = (const int*)d_in[3];
  const float* g0    = (const float*)d_in[4];
  const float* b0    = (const float*)d_in[5];
  const float* W1    = (const float*)d_in[6];
  const float* b1    = (const float*)d_in[7];
  const float* g1    = (const float*)d_in[8];
  const float* be1   = (const float*)d_in[9];
  const float* W2    = (const float*)d_in[10];
  const float* b2    = (const float*)d_in[11];
  const float* g2    = (const float*)d_in[12];
  const float* be2   = (const float*)d_in[13];
  const float* W3    = (const float*)d_in[14];
  const float* b3    = (const float*)d_in[15];
  const float* g3    = (const float*)d_in[16];
  const float* be3   = (const float*)d_in[17];
  const float* W4    = (const float*)d_in[18];
  const float* b4    = (const float*)d_in[19];

  char* ws = (char*)d_ws;
  float* c_pa    = (float*)(ws + 0);
  float* w_t     = (float*)(ws + 1024);
  float* c_g     = (float*)(ws + 2048);
  float* c_const = (float*)(ws + 3072);
  float* scal    = (float*)(ws + 4096);
  unsigned long long* adj = (unsigned long long*)(ws + 4608);
  float* wzT = (float*)(ws + 5120);                       // 64 KB
  float* wzZ = (float*)(ws + 70656);                      // 64 KB
  unsigned short* W2Ah = (unsigned short*)(ws + 136192);  // 64 KB
  unsigned short* W2Al = (unsigned short*)(ws + 201728);  // 64 KB
  unsigned short* W3Ah = (unsigned short*)(ws + 267264);  // 16 KB
  unsigned short* W3Al = (unsigned short*)(ws + 283648);  // 16 KB
  unsigned short* W4Ah = (unsigned short*)(ws + 300032);  // 8 KB
  unsigned short* W4Al = (unsigned short*)(ws + 308224);  // 8 KB
  float* st = (float*)(ws + 316416);                      // 400 floats
  unsigned char* nxt  = (unsigned char*)(ws + 318464);    // 2 MB
  unsigned char* cmap = (unsigned char*)(ws + 2415616);   // 16 KB
  int* startz = (int*)(ws + 2432000);                     // 1 KB
  unsigned char* zones = (unsigned char*)(ws + 2433024);  // 32 KB

  k_prep<<<1, 256, 0, stream>>>(pa, g0, b0, W1, b1, c_pa, w_t, c_g, c_const,
                                scal, wzT, wzZ);
  k_prep2<<<1, 128, 0, stream>>>(c_pa, w_t, c_g, c_const, wzT, st);
  k_scal2st<<<1, 64, 0, stream>>>(scal, st);
  k_adj<<<1, 256, 0, stream>>>(ei, adj);
  k_wsplit<<<176, 256, 0, stream>>>(W2, W3, W4, W2Ah, W2Al, W3Ah, W3Al, W4Ah, W4Al);
  k_pass1<<<32768, 256, 0, stream>>>(times, c_pa, w_t, c_g, c_const, wzT, st,
                                     W2Ah, W2Al, W3Ah, W3Al, W4Ah, W4Al,
                                     b2, b3, b4, g1, be1, g2, be2, g3, be3,
                                     adj, nxt);
  k_scan_a<<<256, 64, 0, stream>>>(nxt, cmap);
  k_scan_b<<<1, 64, 0, stream>>>(cmap, startz);
  k_scan_c<<<256, 64, 0, stream>>>(nxt, startz, zones);
  k_pass2m<<<512, 256, 0, stream>>>(times, zones, c_pa, w_t, c_g, c_const,
                                    wzZ, st, W2Ah, W2Al, W3Ah, W3Al, W4Ah, W4Al,
                                    b2, b3, b4, g1, be1, g2, be2, g3, be3,
                                    adj, (float*)d_out);
}

// Round 8
// 793.429 us; speedup vs baseline: 1.6245x; 1.6245x over previous
//
#include <hip/hip_runtime.h>
#include <stdint.h>

typedef __attribute__((ext_vector_type(8))) short bf16x8;
typedef __attribute__((ext_vector_type(4))) float f32x4;
typedef __attribute__((ext_vector_type(4))) unsigned int u32x4;
typedef __attribute__((ext_vector_type(2))) unsigned int u32x2;

#define MFMA(a, b, c) __builtin_amdgcn_mfma_f32_16x16x32_bf16(a, b, c, 0, 0, 0)

__device__ __forceinline__ unsigned short f2b(float x) {
  unsigned u = __float_as_uint(x);
  return (unsigned short)((u + 0x7fffu + ((u >> 16) & 1u)) >> 16);
}
__device__ __forceinline__ float b2f(unsigned short h) {
  return __uint_as_float(((unsigned)h) << 16);
}

// truncation-based Dekker split of two fp32 into packed bf16 hi/lo dwords
struct u2 { unsigned hi, lo; };
__device__ __forceinline__ u2 split2(float h0, float h1) {
  unsigned u0 = __float_as_uint(h0), u1 = __float_as_uint(h1);
  u2 r;
  r.hi = (u0 >> 16) | (u1 & 0xffff0000u);
  float r0 = h0 - __uint_as_float(u0 & 0xffff0000u);
  float r1 = h1 - __uint_as_float(u1 & 0xffff0000u);
  r.lo = (__float_as_uint(r0) >> 16) | (__float_as_uint(r1) & 0xffff0000u);
  return r;
}

// scratch swizzle (used by k_pass2m only)
#define SWZ(row, col) ((col) ^ ((((row) >> 2) & 1) << 4) ^ ((((row) >> 3) & 1) << 2))

// ---------------- setup kernels ----------------

__global__ void k_prep(const float* __restrict__ pa, const float* __restrict__ g0,
                       const float* __restrict__ b0, const float* __restrict__ W1,
                       const float* __restrict__ b1,
                       float* __restrict__ c_pa, float* __restrict__ w_t,
                       float* __restrict__ c_g, float* __restrict__ c_const,
                       float* __restrict__ scal, float* __restrict__ wzT,
                       float* __restrict__ wzZ) {
  int j = threadIdx.x;  // 256 threads, one per W1 row
  const float* wr = W1 + j * 97;
  float cg = 0.f, cc = 0.f, cp = 0.f;
  for (int k = 0; k < 97; ++k) { float w = wr[k]; cg += w * g0[k]; cc += w * b0[k]; }
  for (int k = 0; k < 32; ++k) cp += wr[k] * g0[k] * pa[k];
  c_g[j] = cg;
  c_const[j] = cc + b1[j];
  c_pa[j] = cp;
  w_t[j] = wr[32] * g0[32];
  for (int z = 0; z < 64; ++z) {
    float v = wr[33 + z] * g0[33 + z];
    wzT[j * 64 + z] = v;     // [k][z]
    wzZ[z * 256 + j] = v;    // [z][k]
  }
  if (j == 0) {
    float s = 0.f, q = 0.f;
    for (int k = 0; k < 32; ++k) { float x = pa[k]; s += x; q += x * x; }
    scal[0] = s; scal[1] = q;
  }
}

// st[0..383]: per-z tables; st[384..385]: scal; st[386..399]: Gram terms
__global__ void k_prep2(const float* __restrict__ c_pa, const float* __restrict__ w_t,
                        const float* __restrict__ c_g, const float* __restrict__ c_const,
                        const float* __restrict__ wzT, float* __restrict__ st) {
  int tid = threadIdx.x;  // 128
  if (tid < 64) {
    int z = tid;
    float A = 0.f, Q = 0.f, dpa = 0.f, dwt = 0.f, dcg = 0.f, dcc = 0.f;
    for (int k = 0; k < 256; ++k) {
      float wz = wzT[k * 64 + z];
      A += wz; Q = fmaf(wz, wz, Q);
      dpa = fmaf(c_pa[k], wz, dpa);
      dwt = fmaf(w_t[k], wz, dwt);
      dcg = fmaf(c_g[k], wz, dcg);
      dcc = fmaf(c_const[k], wz, dcc);
    }
    st[z] = A; st[64 + z] = Q; st[128 + z] = dpa;
    st[192 + z] = dwt; st[256 + z] = dcg; st[320 + z] = dcc;
  } else {
    int lane = tid - 64;  // wave 1
    float acc[14];
    #pragma unroll
    for (int m = 0; m < 14; ++m) acc[m] = 0.f;
    for (int k = lane; k < 256; k += 64) {
      float P = c_pa[k], W = w_t[k], G = c_g[k], C = c_const[k];
      acc[0] += P; acc[1] += W; acc[2] += G; acc[3] += C;
      acc[4] = fmaf(P, P, acc[4]); acc[5] = fmaf(P, W, acc[5]);
      acc[6] = fmaf(P, G, acc[6]); acc[7] = fmaf(P, C, acc[7]);
      acc[8] = fmaf(W, W, acc[8]); acc[9] = fmaf(W, G, acc[9]);
      acc[10] = fmaf(W, C, acc[10]); acc[11] = fmaf(G, G, acc[11]);
      acc[12] = fmaf(G, C, acc[12]); acc[13] = fmaf(C, C, acc[13]);
    }
    #pragma unroll
    for (int off = 1; off < 64; off <<= 1) {
      #pragma unroll
      for (int m = 0; m < 14; ++m) acc[m] += __shfl_xor(acc[m], off, 64);
    }
    if (lane == 0) {
      #pragma unroll
      for (int m = 0; m < 14; ++m) st[386 + m] = acc[m];
    }
  }
}

__global__ void k_scal2st(const float* __restrict__ scal, float* __restrict__ st) {
  if (threadIdx.x < 2) st[384 + threadIdx.x] = scal[threadIdx.x];
}

__global__ void k_adj(const int* __restrict__ ei, unsigned long long* __restrict__ adj) {
  int t = threadIdx.x;  // 256
  if (t < 64) adj[t] = 1ull << t;
  __syncthreads();
  int u = ei[t] & 63, v = ei[256 + t] & 63;
  atomicOr(&adj[u], 1ull << v);
  atomicOr(&adj[v], 1ull << u);
}

// Pre-split weights into MFMA A-fragment order, bf16 hi/lo (RNE, done once).
__global__ void k_wsplit(const float* __restrict__ W2, const float* __restrict__ W3,
                         const float* __restrict__ W4,
                         unsigned short* __restrict__ W2Ah, unsigned short* __restrict__ W2Al,
                         unsigned short* __restrict__ W3Ah, unsigned short* __restrict__ W3Al,
                         unsigned short* __restrict__ W4Ah, unsigned short* __restrict__ W4Al) {
  int idx = blockIdx.x * 256 + threadIdx.x;
  float w; unsigned short* ph; unsigned short* pl; int o;
  if (idx < 32768) {                       // W2 [128][256]
    int mt = idx >> 12, kt = (idx >> 9) & 7, lane = (idx >> 3) & 63, j = idx & 7;
    int m = mt * 16 + (lane & 15), k = kt * 32 + (lane >> 4) * 8 + j;
    w = W2[m * 256 + k]; ph = W2Ah; pl = W2Al; o = idx;
  } else if (idx < 40960) {                // W3 [64][128]
    int r = idx - 32768;
    int mt = r >> 11, kt = (r >> 9) & 3, lane = (r >> 3) & 63, j = r & 7;
    int m = mt * 16 + (lane & 15), k = kt * 32 + (lane >> 4) * 8 + j;
    w = W3[m * 128 + k]; ph = W3Ah; pl = W3Al; o = r;
  } else if (idx < 45056) {                // W4 [64][64]
    int r = idx - 40960;
    int mt = r >> 10, kt = (r >> 9) & 1, lane = (r >> 3) & 63, j = r & 7;
    int m = mt * 16 + (lane & 15), k = kt * 32 + (lane >> 4) * 8 + j;
    w = W4[m * 64 + k]; ph = W4Ah; pl = W4Al; o = r;
  } else return;
  unsigned short hb = f2b(w);
  ph[o] = hb;
  pl[o] = f2b(w - b2f(hb));
}

// ---------------- pass 1: transition table next[i][z] ----------------
// 16KB frag region (K=64 chunks), shared P/Q LN tables (1 rsqrt per layer).
// launch_bounds(256,5): combined VGPR+AGPR cap ~102 (no spill), 5 blocks/CU.

__global__ __launch_bounds__(256, 5) void k_pass1(
    const float* __restrict__ times,
    const float* __restrict__ c_pa, const float* __restrict__ w_t,
    const float* __restrict__ c_g, const float* __restrict__ c_const,
    const float* __restrict__ wzT, const float* __restrict__ st,
    const unsigned short* __restrict__ W2Ah, const unsigned short* __restrict__ W2Al,
    const unsigned short* __restrict__ W3Ah, const unsigned short* __restrict__ W3Al,
    const unsigned short* __restrict__ W4Ah, const unsigned short* __restrict__ W4Al,
    const float* __restrict__ b2, const float* __restrict__ b3,
    const float* __restrict__ b4,
    const float* __restrict__ g1, const float* __restrict__ be1,
    const float* __restrict__ g2, const float* __restrict__ be2,
    const float* __restrict__ g3, const float* __restrict__ be3,
    const unsigned long long* __restrict__ adj,
    unsigned char* __restrict__ nxt) {
  __shared__ __align__(16) char region[16384];   // [2kt][4nt][64][8] hi | lo
  __shared__ float u_lds[256];
  __shared__ float ps[512];                      // partials; P/Q tables; pk alias

  unsigned short* Bhi = (unsigned short*)region;
  unsigned short* Blo = (unsigned short*)(region + 8192);
  unsigned long long* pk = (unsigned long long*)ps;

  const int tid = threadIdx.x;
  const int lane = tid & 63;          // lane == zone z for producer phases
  const int l15 = lane & 15;
  const int lhi = lane >> 4;
  const int w = __builtin_amdgcn_readfirstlane(tid >> 6);
  const int i = blockIdx.x;

  const float t = times[i];
  const float m0 = (st[384] + t + 1.0f) * (1.0f / 97.0f);
  const float e2 = (st[385] + t * t + 1.0f) * (1.0f / 97.0f);
  const float alpha = 1.0f / sqrtf(e2 - m0 * m0 + 1e-5f);
  const float gma = -m0 * alpha;

  const f32x4 zero4 = {0.f, 0.f, 0.f, 0.f};

  // ---- u(k) once per k + block sums; closed-form LN1 stats per z ----
  {
    int k = tid;
    float u = fmaf(t, w_t[k], c_pa[k]);
    u = fmaf(alpha, u, c_const[k]);
    u = fmaf(gma, c_g[k], u);
    u_lds[k] = u;
    float su = u, sq = u * u;
    #pragma unroll
    for (int off = 1; off < 64; off <<= 1) {
      su += __shfl_xor(su, off, 64);
      sq += __shfl_xor(sq, off, 64);
    }
    if (lane == 0) { ps[w] = su; ps[256 + w] = sq; }
  }
  __syncthreads();
  float mu1, inv1;
  {
    float U1 = ps[0] + ps[1] + ps[2] + ps[3];
    float Qu = ps[256] + ps[257] + ps[258] + ps[259];
    float A1 = st[lane], Qz = st[64 + lane];
    float dpa = st[128 + lane], dwt = st[192 + lane];
    float dcg = st[256 + lane], dcc = st[320 + lane];
    float s1 = fmaf(alpha, A1, U1);
    float uwz = fmaf(alpha, fmaf(t, dwt, dpa), fmaf(gma, dcg, dcc));
    float s2 = Qu + 2.0f * alpha * uwz + alpha * alpha * Qz;
    mu1 = s1 * (1.0f / 256.0f);
    inv1 = 1.0f / sqrtf(s2 * (1.0f / 256.0f) - mu1 * mu1 + 1e-5f);
  }

  // ---- GEMM1: h2[128][64] = W2 @ h1, K=256 in 4 chunks of 64 ----
  f32x4 acc[2][4];
  #pragma unroll
  for (int a = 0; a < 2; ++a)
    #pragma unroll
    for (int b = 0; b < 4; ++b) acc[a][b] = zero4;

  for (int kc = 0; kc < 4; ++kc) {
    if (kc) __syncthreads();          // previous chunk's MFMA readers done
    // producers: 2 octets per wave: o = w*2+q, k = kc*64 + o*8 + j, z = lane
    #pragma unroll
    for (int q = 0; q < 2; ++q) {
      int o = w * 2 + q;
      int kb = kc * 64 + o * 8;
      f32x4 u0 = *(const f32x4*)(u_lds + kb);
      f32x4 u1v = *(const f32x4*)(u_lds + kb + 4);
      float hbuf[8];
      #pragma unroll
      for (int j = 0; j < 8; ++j) {
        int k = kb + j;
        float u = (j < 4) ? u0[j] : u1v[j - 4];
        float p = fmaf(alpha, wzT[k * 64 + lane], u);
        float gi = g1[k] * inv1;
        float bb = fmaf(-mu1, gi, be1[k]);
        hbuf[j] = fmaxf(fmaf(p, gi, bb), 0.f);
      }
      u32x4 vh, vl;
      #pragma unroll
      for (int e = 0; e < 4; ++e) {
        u2 s = split2(hbuf[2 * e], hbuf[2 * e + 1]);
        vh[e] = s.hi; vl[e] = s.lo;
      }
      int slotd = (((o >> 2) * 4 + lhi) * 64 + (o & 3) * 16 + l15) * 4;
      *(u32x4*)((unsigned*)Bhi + slotd) = vh;
      *(u32x4*)((unsigned*)Blo + slotd) = vl;
    }
    __syncthreads();
    // MFMA: wave owns M rows [32w, 32w+32)
    #pragma unroll
    for (int kt = 0; kt < 2; ++kt) {
      int ktg = kc * 2 + kt;
      bf16x8 a0h = *(const bf16x8*)(W2Ah + (((2 * w + 0) * 8 + ktg) * 64 + lane) * 8);
      bf16x8 a0l = *(const bf16x8*)(W2Al + (((2 * w + 0) * 8 + ktg) * 64 + lane) * 8);
      bf16x8 a1h = *(const bf16x8*)(W2Ah + (((2 * w + 1) * 8 + ktg) * 64 + lane) * 8);
      bf16x8 a1l = *(const bf16x8*)(W2Al + (((2 * w + 1) * 8 + ktg) * 64 + lane) * 8);
      #pragma unroll
      for (int nt = 0; nt < 4; ++nt) {
        bf16x8 bh = *(const bf16x8*)(Bhi + ((kt * 4 + nt) * 64 + lane) * 8);
        bf16x8 bl = *(const bf16x8*)(Blo + ((kt * 4 + nt) * 64 + lane) * 8);
        acc[0][nt] = MFMA(a0h, bh, acc[0][nt]);
        acc[0][nt] = MFMA(a0h, bl, acc[0][nt]);
        acc[0][nt] = MFMA(a0l, bh, acc[0][nt]);
        acc[1][nt] = MFMA(a1h, bh, acc[1][nt]);
        acc[1][nt] = MFMA(a1h, bl, acc[1][nt]);
        acc[1][nt] = MFMA(a1l, bh, acc[1][nt]);
      }
    }
  }

  // +b2, LN2 partial sums (per column over 128 rows)
  #pragma unroll
  for (int mti = 0; mti < 2; ++mti) {
    f32x4 bv = *(const f32x4*)(b2 + w * 32 + mti * 16 + lhi * 4);
    #pragma unroll
    for (int nt = 0; nt < 4; ++nt) acc[mti][nt] += bv;
  }
  #pragma unroll
  for (int nt = 0; nt < 4; ++nt) {
    float x1 = 0.f, x2 = 0.f;
    #pragma unroll
    for (int mti = 0; mti < 2; ++mti)
      #pragma unroll
      for (int r = 0; r < 4; ++r) { float v = acc[mti][nt][r]; x1 += v; x2 += v * v; }
    x1 += __shfl_xor(x1, 16, 64); x1 += __shfl_xor(x1, 32, 64);
    x2 += __shfl_xor(x2, 16, 64); x2 += __shfl_xor(x2, 32, 64);
    if (lane < 16) {
      ps[w * 64 + nt * 16 + lane] = x1;
      ps[256 + w * 64 + nt * 16 + lane] = x2;
    }
  }
  __syncthreads();
  // P/Q table for LN2 (wave 0 only; one rsqrt per column)
  if (w == 0) {
    int c = lane;
    float a = ps[c] + ps[64 + c] + ps[128 + c] + ps[192 + c];
    float b = ps[256 + c] + ps[320 + c] + ps[384 + c] + ps[448 + c];
    float mu = a * (1.0f / 128.0f);
    float inv = 1.0f / sqrtf(b * (1.0f / 128.0f) - mu * mu + 1e-5f);
    ps[c] = inv;               // P
    ps[64 + c] = -mu * inv;    // Q
  }
  __syncthreads();

  // ---- GEMM2: h3[64][64] = W3 @ h2, K=128 in 2 chunks of 64 ----
  f32x4 acc2[4];
  #pragma unroll
  for (int b = 0; b < 4; ++b) acc2[b] = zero4;

  for (int kc2 = 0; kc2 < 2; ++kc2) {
    if ((w >> 1) == kc2) {            // waves 2*kc2, 2*kc2+1 own these h2 rows
      f32x4 g2v[2], be2v[2];
      #pragma unroll
      for (int mti = 0; mti < 2; ++mti) {
        g2v[mti]  = *(const f32x4*)(g2  + w * 32 + mti * 16 + lhi * 4);
        be2v[mti] = *(const f32x4*)(be2 + w * 32 + mti * 16 + lhi * 4);
      }
      #pragma unroll
      for (int nt = 0; nt < 4; ++nt) {
        int c = nt * 16 + l15;
        float P = ps[c], Q = ps[64 + c];
        #pragma unroll
        for (int mti = 0; mti < 2; ++mti) {
          float h[4];
          #pragma unroll
          for (int r = 0; r < 4; ++r) {
            float G = g2v[mti][r];
            h[r] = fmaxf(fmaf(acc[mti][nt][r], G * P, fmaf(G, Q, be2v[mti][r])), 0.f);
          }
          u2 s01 = split2(h[0], h[1]);
          u2 s23 = split2(h[2], h[3]);
          int base = (((w - 2 * kc2) * 4 + nt) * 64 +
                      (mti * 2 + (lhi >> 1)) * 16 + l15) * 8 + (lhi & 1) * 4;
          u32x2 vh = {s01.hi, s23.hi};
          u32x2 vl = {s01.lo, s23.lo};
          *(u32x2*)(Bhi + base) = vh;
          *(u32x2*)(Blo + base) = vl;
        }
      }
    }
    __syncthreads();
    #pragma unroll
    for (int kt = 0; kt < 2; ++kt) {
      int ktg = kc2 * 2 + kt;
      bf16x8 ah = *(const bf16x8*)(W3Ah + ((w * 4 + ktg) * 64 + lane) * 8);
      bf16x8 al = *(const bf16x8*)(W3Al + ((w * 4 + ktg) * 64 + lane) * 8);
      #pragma unroll
      for (int nt = 0; nt < 4; ++nt) {
        bf16x8 bh = *(const bf16x8*)(Bhi + ((kt * 4 + nt) * 64 + lane) * 8);
        bf16x8 bl = *(const bf16x8*)(Blo + ((kt * 4 + nt) * 64 + lane) * 8);
        acc2[nt] = MFMA(ah, bh, acc2[nt]);
        acc2[nt] = MFMA(ah, bl, acc2[nt]);
        acc2[nt] = MFMA(al, bh, acc2[nt]);
      }
    }
    __syncthreads();
  }

  // +b3, LN3 partial sums
  {
    f32x4 bv = *(const f32x4*)(b3 + w * 16 + lhi * 4);
    #pragma unroll
    for (int nt = 0; nt < 4; ++nt) acc2[nt] += bv;
  }
  #pragma unroll
  for (int nt = 0; nt < 4; ++nt) {
    float x1 = 0.f, x2 = 0.f;
    #pragma unroll
    for (int r = 0; r < 4; ++r) { float v = acc2[nt][r]; x1 += v; x2 += v * v; }
    x1 += __shfl_xor(x1, 16, 64); x1 += __shfl_xor(x1, 32, 64);
    x2 += __shfl_xor(x2, 16, 64); x2 += __shfl_xor(x2, 32, 64);
    if (lane < 16) {
      ps[w * 64 + nt * 16 + lane] = x1;
      ps[256 + w * 64 + nt * 16 + lane] = x2;
    }
  }
  __syncthreads();
  if (w == 0) {
    int c = lane;
    float a = ps[c] + ps[64 + c] + ps[128 + c] + ps[192 + c];
    float b = ps[256 + c] + ps[320 + c] + ps[384 + c] + ps[448 + c];
    float mu = a * (1.0f / 64.0f);
    float inv = 1.0f / sqrtf(b * (1.0f / 64.0f) - mu * mu + 1e-5f);
    ps[c] = inv;               // P
    ps[64 + c] = -mu * inv;    // Q
  }
  __syncthreads();

  // ---- B3 producers: all waves, direct scatter from acc2 ----
  {
    f32x4 g3v  = *(const f32x4*)(g3  + w * 16 + lhi * 4);
    f32x4 be3v = *(const f32x4*)(be3 + w * 16 + lhi * 4);
    #pragma unroll
    for (int nt = 0; nt < 4; ++nt) {
      int c = nt * 16 + l15;
      float P = ps[c], Q = ps[64 + c];
      float h[4];
      #pragma unroll
      for (int r = 0; r < 4; ++r) {
        float G = g3v[r];
        h[r] = fmaxf(fmaf(acc2[nt][r], G * P, fmaf(G, Q, be3v[r])), 0.f);
      }
      u2 s01 = split2(h[0], h[1]);
      u2 s23 = split2(h[2], h[3]);
      int base = (((w >> 1) * 4 + nt) * 64 +
                  ((w & 1) * 2 + (lhi >> 1)) * 16 + l15) * 8 + (lhi & 1) * 4;
      u32x2 vh = {s01.hi, s23.hi};
      u32x2 vl = {s01.lo, s23.lo};
      *(u32x2*)(Bhi + base) = vh;
      *(u32x2*)(Blo + base) = vl;
    }
  }
  __syncthreads();

  // ---- GEMM3: raw[64][64] = W4 @ h3 ----
  f32x4 acc3[4];
  #pragma unroll
  for (int b = 0; b < 4; ++b) acc3[b] = zero4;
  #pragma unroll
  for (int kt = 0; kt < 2; ++kt) {
    bf16x8 ah = *(const bf16x8*)(W4Ah + ((w * 2 + kt) * 64 + lane) * 8);
    bf16x8 al = *(const bf16x8*)(W4Al + ((w * 2 + kt) * 64 + lane) * 8);
    #pragma unroll
    for (int nt = 0; nt < 4; ++nt) {
      bf16x8 bh = *(const bf16x8*)(Bhi + ((kt * 4 + nt) * 64 + lane) * 8);
      bf16x8 bl = *(const bf16x8*)(Blo + ((kt * 4 + nt) * 64 + lane) * 8);
      acc3[nt] = MFMA(ah, bh, acc3[nt]);
      acc3[nt] = MFMA(ah, bl, acc3[nt]);
      acc3[nt] = MFMA(al, bh, acc3[nt]);
    }
  }
  f32x4 b4v = *(const f32x4*)(b4 + w * 16 + lhi * 4);
  unsigned long long kbest[4];
  #pragma unroll
  for (int nt = 0; nt < 4; ++nt) {
    unsigned long long am = adj[nt * 16 + l15];
    unsigned long long kb = 0ull;
    #pragma unroll
    for (int r = 0; r < 4; ++r) {
      int o = w * 16 + lhi * 4 + r;
      float raw = acc3[nt][r] + b4v[r];
      float val = ((am >> o) & 1ull) ? raw : -__builtin_huge_valf();
      unsigned u = __float_as_uint(val);
      u = (u & 0x80000000u) ? ~u : (u | 0x80000000u);
      unsigned long long key = ((unsigned long long)u << 6) | (unsigned long long)(63 - o);
      if (key > kb) kb = key;
    }
    unsigned long long oth = __shfl_xor(kb, 16, 64); if (oth > kb) kb = oth;
    oth = __shfl_xor(kb, 32, 64); if (oth > kb) kb = oth;
    kbest[nt] = kb;
  }
  if (lane < 16) {
    #pragma unroll
    for (int nt = 0; nt < 4; ++nt) pk[w * 64 + nt * 16 + lane] = kbest[nt];
  }
  __syncthreads();
  if (tid < 64) {
    unsigned long long k0 = pk[tid], k1 = pk[64 + tid];
    unsigned long long k2 = pk[128 + tid], k3 = pk[192 + tid];
    unsigned long long a = k0 > k1 ? k0 : k1;
    unsigned long long b = k2 > k3 ? k2 : k3;
    unsigned long long bb = a > b ? a : b;
    nxt[(size_t)i * 64 + tid] = (unsigned char)(63u - (unsigned)(bb & 63ull));
  }
}

// ---------------- trajectory via parallel map-composition scan ----------------

__global__ void k_scan_a(const unsigned char* __restrict__ nxt,
                         unsigned char* __restrict__ cmap) {
  int c = blockIdx.x, lane = threadIdx.x;
  int g = lane;
  const unsigned char* p = nxt + (size_t)c * 128 * 64;
  for (int s = 0; s < 128; ++s) {
    int sig = p[s * 64 + lane];
    g = __shfl(sig, g, 64);
  }
  cmap[c * 64 + lane] = (unsigned char)g;
}

__global__ void k_scan_b(const unsigned char* __restrict__ cmap,
                         int* __restrict__ startz) {
  int lane = threadIdx.x;
  int cur = 0;
  for (int c = 0; c < 256; ++c) {
    if (lane == 0) startz[c] = cur;
    int row = cmap[c * 64 + lane];
    cur = __shfl(row, cur, 64);
  }
}

__global__ void k_scan_c(const unsigned char* __restrict__ nxt,
                         const int* __restrict__ startz,
                         unsigned char* __restrict__ zones) {
  int c = blockIdx.x, lane = threadIdx.x;
  int cur = startz[c];
  const unsigned char* p = nxt + (size_t)c * 128 * 64;
  for (int s = 0; s < 128; ++s) {
    if (lane == 0) zones[c * 128 + s] = (unsigned char)cur;
    int row = p[s * 64 + lane];
    cur = __shfl(row, cur, 64);
  }
}

// ---------------- pass 2m: logits for actual zones, 64 timesteps/block ----------------

__global__ __launch_bounds__(256, 2) void k_pass2m(
    const float* __restrict__ times, const unsigned char* __restrict__ zones,
    const float* __restrict__ c_pa, const float* __restrict__ w_t,
    const float* __restrict__ c_g, const float* __restrict__ c_const,
    const float* __restrict__ wzZ, const float* __restrict__ st,
    const unsigned short* __restrict__ W2Ah, const unsigned short* __restrict__ W2Al,
    const unsigned short* __restrict__ W3Ah, const unsigned short* __restrict__ W3Al,
    const unsigned short* __restrict__ W4Ah, const unsigned short* __restrict__ W4Al,
    const float* __restrict__ b2, const float* __restrict__ b3,
    const float* __restrict__ b4,
    const float* __restrict__ g1, const float* __restrict__ be1,
    const float* __restrict__ g2, const float* __restrict__ be2,
    const float* __restrict__ g3, const float* __restrict__ be3,
    const unsigned long long* __restrict__ adj,
    float* __restrict__ out) {
  __shared__ __align__(16) char region[32768];
  __shared__ float ps1[256], ps2[256];
  __shared__ unsigned long long am_lds[64];

  unsigned short* B1hi = (unsigned short*)region;
  unsigned short* B1lo = (unsigned short*)(region + 16384);
  float* h2p = (float*)region;
  unsigned short* B2hi = (unsigned short*)region;
  unsigned short* B2lo = (unsigned short*)(region + 16384);
  float* h3p = (float*)region;
  unsigned short* B3hi = (unsigned short*)(region + 16384);
  unsigned short* B3lo = (unsigned short*)(region + 24576);
  float* outT = (float*)region;

  const int tid = threadIdx.x;
  const int lane = tid & 63;
  const int l15 = lane & 15;
  const int lhi = lane >> 4;
  const int w = __builtin_amdgcn_readfirstlane(tid >> 6);
  const int i0 = blockIdx.x * 64;

  const float t = times[i0 + lane];
  const int z = zones[i0 + lane];
  const int zrow = z << 8;
  if (tid < 64) am_lds[tid] = adj[zones[i0 + tid]];

  const float m0 = (st[384] + t + 1.0f) * (1.0f / 97.0f);
  const float e2 = (st[385] + t * t + 1.0f) * (1.0f / 97.0f);
  const float a0 = 1.0f / sqrtf(e2 - m0 * m0 + 1e-5f);
  const float a1 = a0 * t;
  const float a2 = -m0 * a0;

  float mu1, inv1;
  {
    float SP = st[386], SW = st[387], SG = st[388], SC = st[389];
    float PP = st[390], PW = st[391], PG = st[392], PC = st[393];
    float WW = st[394], WG = st[395], WC = st[396];
    float GG = st[397], GC = st[398], CC = st[399];
    float U1 = a0 * SP + a1 * SW + a2 * SG + SC;
    float s1 = fmaf(a0, st[z], U1);
    float Qu = a0 * a0 * PP + a1 * a1 * WW + a2 * a2 * GG + CC
             + 2.0f * (a0 * a1 * PW + a0 * a2 * PG + a0 * PC
                       + a1 * a2 * WG + a1 * WC + a2 * GC);
    float uwz = a0 * st[128 + z] + a1 * st[192 + z] + a2 * st[256 + z] + st[320 + z];
    float s2 = Qu + 2.0f * a0 * uwz + a0 * a0 * st[64 + z];
    mu1 = s1 * (1.0f / 256.0f);
    inv1 = 1.0f / sqrtf(s2 * (1.0f / 256.0f) - mu1 * mu1 + 1e-5f);
  }

  const f32x4 zero4 = {0.f, 0.f, 0.f, 0.f};
  f32x4 acc[2][4];
  #pragma unroll
  for (int a = 0; a < 2; ++a)
    #pragma unroll
    for (int b = 0; b < 4; ++b) acc[a][b] = zero4;

  for (int kc = 0; kc < 2; ++kc) {
    if (kc) __syncthreads();
    #pragma unroll
    for (int q = 0; q < 4; ++q) {
      int kb = kc * 128 + w * 32 + q * 8;
      float hbuf[8];
      #pragma unroll
      for (int j = 0; j < 8; ++j) {
        int k = kb + j;
        float u = fmaf(a0, c_pa[k], fmaf(a1, w_t[k], fmaf(a2, c_g[k], c_const[k])));
        float p = fmaf(a0, wzZ[zrow + k], u);
        float gi = g1[k] * inv1;
        float bb = fmaf(-mu1, gi, be1[k]);
        hbuf[j] = fmaxf(fmaf(p, gi, bb), 0.f);
      }
      u32x4 vh, vl;
      #pragma unroll
      for (int e = 0; e < 4; ++e) {
        u2 s = split2(hbuf[2 * e], hbuf[2 * e + 1]);
        vh[e] = s.hi; vl[e] = s.lo;
      }
      int slotd = ((w * 4 + lhi) * 64 + q * 16 + l15) * 4;
      *(u32x4*)((unsigned*)B1hi + slotd) = vh;
      *(u32x4*)((unsigned*)B1lo + slotd) = vl;
    }
    __syncthreads();
    for (int kt = 0; kt < 4; ++kt) {
      int ktg = kc * 4 + kt;
      bf16x8 a0h = *(const bf16x8*)(W2Ah + (((2 * w + 0) * 8 + ktg) * 64 + lane) * 8);
      bf16x8 a0l = *(const bf16x8*)(W2Al + (((2 * w + 0) * 8 + ktg) * 64 + lane) * 8);
      bf16x8 a1h = *(const bf16x8*)(W2Ah + (((2 * w + 1) * 8 + ktg) * 64 + lane) * 8);
      bf16x8 a1l = *(const bf16x8*)(W2Al + (((2 * w + 1) * 8 + ktg) * 64 + lane) * 8);
      #pragma unroll
      for (int nt = 0; nt < 4; ++nt) {
        bf16x8 bh = *(const bf16x8*)(B1hi + ((kt * 4 + nt) * 64 + lane) * 8);
        bf16x8 bl = *(const bf16x8*)(B1lo + ((kt * 4 + nt) * 64 + lane) * 8);
        acc[0][nt] = MFMA(a0h, bh, acc[0][nt]);
        acc[0][nt] = MFMA(a0h, bl, acc[0][nt]);
        acc[0][nt] = MFMA(a0l, bh, acc[0][nt]);
        acc[1][nt] = MFMA(a1h, bh, acc[1][nt]);
        acc[1][nt] = MFMA(a1h, bl, acc[1][nt]);
        acc[1][nt] = MFMA(a1l, bh, acc[1][nt]);
      }
    }
  }
  #pragma unroll
  for (int mti = 0; mti < 2; ++mti) {
    f32x4 bv = *(const f32x4*)(b2 + w * 32 + mti * 16 + lhi * 4);
    #pragma unroll
    for (int nt = 0; nt < 4; ++nt) acc[mti][nt] += bv;
  }
  {
    float sa[4], sb[4];
    #pragma unroll
    for (int nt = 0; nt < 4; ++nt) {
      float x1 = 0.f, x2 = 0.f;
      #pragma unroll
      for (int mti = 0; mti < 2; ++mti)
        #pragma unroll
        for (int r = 0; r < 4; ++r) { float v = acc[mti][nt][r]; x1 += v; x2 += v * v; }
      x1 += __shfl_xor(x1, 16, 64); x1 += __shfl_xor(x1, 32, 64);
      x2 += __shfl_xor(x2, 16, 64); x2 += __shfl_xor(x2, 32, 64);
      sa[nt] = x1; sb[nt] = x2;
    }
    if (lane < 16) {
      #pragma unroll
      for (int nt = 0; nt < 4; ++nt) {
        ps1[w * 64 + nt * 16 + lane] = sa[nt];
        ps2[w * 64 + nt * 16 + lane] = sb[nt];
      }
    }
  }
  __syncthreads();
  #pragma unroll
  for (int mti = 0; mti < 2; ++mti)
    #pragma unroll
    for (int nt = 0; nt < 4; ++nt)
      #pragma unroll
      for (int r = 0; r < 4; ++r) {
        int row = w * 32 + mti * 16 + lhi * 4 + r;
        h2p[row * 64 + SWZ(row, nt * 16 + l15)] = acc[mti][nt][r];
      }
  __syncthreads();

  float mu2, inv2;
  {
    float a = ps1[lane] + ps1[64 + lane] + ps1[128 + lane] + ps1[192 + lane];
    float b = ps2[lane] + ps2[64 + lane] + ps2[128 + lane] + ps2[192 + lane];
    mu2 = a * (1.0f / 128.0f);
    inv2 = 1.0f / sqrtf(b * (1.0f / 128.0f) - mu2 * mu2 + 1e-5f);
  }
  float hv[32];
  #pragma unroll
  for (int mi = 0; mi < 32; ++mi) {
    int row = w * 32 + mi;
    hv[mi] = h2p[row * 64 + SWZ(row, lane)];
  }
  __syncthreads();
  #pragma unroll
  for (int q = 0; q < 4; ++q) {
    float hbuf[8];
    #pragma unroll
    for (int j = 0; j < 8; ++j) {
      int mi = q * 8 + j, mm = w * 32 + mi;
      float gi = g2[mm] * inv2;
      float bb = fmaf(-mu2, gi, be2[mm]);
      hbuf[j] = fmaxf(fmaf(hv[mi], gi, bb), 0.f);
    }
    u32x4 vh, vl;
    #pragma unroll
    for (int e = 0; e < 4; ++e) {
      u2 s = split2(hbuf[2 * e], hbuf[2 * e + 1]);
      vh[e] = s.hi; vl[e] = s.lo;
    }
    int slotd = ((w * 4 + lhi) * 64 + q * 16 + l15) * 4;
    *(u32x4*)((unsigned*)B2hi + slotd) = vh;
    *(u32x4*)((unsigned*)B2lo + slotd) = vl;
  }
  __syncthreads();

  f32x4 acc2[4];
  #pragma unroll
  for (int b = 0; b < 4; ++b) acc2[b] = zero4;
  for (int kt = 0; kt < 4; ++kt) {
    bf16x8 ah = *(const bf16x8*)(W3Ah + ((w * 4 + kt) * 64 + lane) * 8);
    bf16x8 al = *(const bf16x8*)(W3Al + ((w * 4 + kt) * 64 + lane) * 8);
    #pragma unroll
    for (int nt = 0; nt < 4; ++nt) {
      bf16x8 bh = *(const bf16x8*)(B2hi + ((kt * 4 + nt) * 64 + lane) * 8);
      bf16x8 bl = *(const bf16x8*)(B2lo + ((kt * 4 + nt) * 64 + lane) * 8);
      acc2[nt] = MFMA(ah, bh, acc2[nt]);
      acc2[nt] = MFMA(ah, bl, acc2[nt]);
      acc2[nt] = MFMA(al, bh, acc2[nt]);
    }
  }
  {
    f32x4 bv = *(const f32x4*)(b3 + w * 16 + lhi * 4);
    #pragma unroll
    for (int nt = 0; nt < 4; ++nt) acc2[nt] += bv;
  }
  {
    float sa[4], sb[4];
    #pragma unroll
    for (int nt = 0; nt < 4; ++nt) {
      float x1 = 0.f, x2 = 0.f;
      #pragma unroll
      for (int r = 0; r < 4; ++r) { float v = acc2[nt][r]; x1 += v; x2 += v * v; }
      x1 += __shfl_xor(x1, 16, 64); x1 += __shfl_xor(x1, 32, 64);
      x2 += __shfl_xor(x2, 16, 64); x2 += __shfl_xor(x2, 32, 64);
      sa[nt] = x1; sb[nt] = x2;
    }
    if (lane < 16) {
      #pragma unroll
      for (int nt = 0; nt < 4; ++nt) {
        ps1[w * 64 + nt * 16 + lane] = sa[nt];
        ps2[w * 64 + nt * 16 + lane] = sb[nt];
      }
    }
  }
  __syncthreads();
  #pragma unroll
  for (int nt = 0; nt < 4; ++nt)
    #pragma unroll
    for (int r = 0; r < 4; ++r) {
      int row = w * 16 + lhi * 4 + r;
      h3p[row * 64 + SWZ(row, nt * 16 + l15)] = acc2[nt][r];
    }
  __syncthreads();

  float mu3, inv3;
  {
    float a = ps1[lane] + ps1[64 + lane] + ps1[128 + lane] + ps1[192 + lane];
    float b = ps2[lane] + ps2[64 + lane] + ps2[128 + lane] + ps2[192 + lane];
    mu3 = a * (1.0f / 64.0f);
    inv3 = 1.0f / sqrtf(b * (1.0f / 64.0f) - mu3 * mu3 + 1e-5f);
  }
  #pragma unroll
  for (int q = 0; q < 2; ++q) {
    int o = w * 2 + q;
    float hbuf[8];
    #pragma unroll
    for (int j = 0; j < 8; ++j) {
      int mm = o * 8 + j;
      float v = h3p[mm * 64 + SWZ(mm, lane)];
      float gi = g3[mm] * inv3;
      float bb = fmaf(-mu3, gi, be3[mm]);
      hbuf[j] = fmaxf(fmaf(v, gi, bb), 0.f);
    }
    u32x4 vh, vl;
    #pragma unroll
    for (int e = 0; e < 4; ++e) {
      u2 s = split2(hbuf[2 * e], hbuf[2 * e + 1]);
      vh[e] = s.hi; vl[e] = s.lo;
    }
    int slotd = (((o >> 2) * 4 + lhi) * 64 + (o & 3) * 16 + l15) * 4;
    *(u32x4*)((unsigned*)B3hi + slotd) = vh;
    *(u32x4*)((unsigned*)B3lo + slotd) = vl;
  }
  __syncthreads();

  f32x4 acc3[4];
  #pragma unroll
  for (int b = 0; b < 4; ++b) acc3[b] = zero4;
  for (int kt = 0; kt < 2; ++kt) {
    bf16x8 ah = *(const bf16x8*)(W4Ah + ((w * 2 + kt) * 64 + lane) * 8);
    bf16x8 al = *(const bf16x8*)(W4Al + ((w * 2 + kt) * 64 + lane) * 8);
    #pragma unroll
    for (int nt = 0; nt < 4; ++nt) {
      bf16x8 bh = *(const bf16x8*)(B3hi + ((kt * 4 + nt) * 64 + lane) * 8);
      bf16x8 bl = *(const bf16x8*)(B3lo + ((kt * 4 + nt) * 64 + lane) * 8);
      acc3[nt] = MFMA(ah, bh, acc3[nt]);
      acc3[nt] = MFMA(ah, bl, acc3[nt]);
      acc3[nt] = MFMA(al, bh, acc3[nt]);
    }
  }
  f32x4 b4v = *(const f32x4*)(b4 + w * 16 + lhi * 4);
  #pragma unroll
  for (int nt = 0; nt < 4; ++nt) {
    unsigned long long am = am_lds[nt * 16 + l15];
    #pragma unroll
    for (int r = 0; r < 4; ++r) {
      int o = w * 16 + lhi * 4 + r;
      float raw = acc3[nt][r] + b4v[r];
      float predv = ((am >> o) & 1ull) ? raw : -50.0f;
      int b = nt * 16 + l15;
      outT[b * 64 + SWZ(b, o)] = predv;
    }
  }
  __syncthreads();
  {
    int b = tid >> 2, cb = (tid & 3) * 16;
    size_t gbase = ((size_t)(i0 + b)) * 64 + cb;
    #pragma unroll
    for (int c4 = 0; c4 < 4; ++c4) {
      int col = cb + c4 * 4;
      f32x4 v = *(const f32x4*)(outT + b * 64 + SWZ(b, col));
      *(f32x4*)(out + gbase + c4 * 4) = v;
    }
  }
}

// ---------------- launch ----------------

extern "C" void kernel_launch(void* const* d_in, const int* in_sizes, int n_in,
                              void* d_out, int out_size, void* d_ws, size_t ws_size,
                              hipStream_t stream) {
  const float* pa    = (const float*)d_in[0];
  const float* times = (const float*)d_in[1];
  const int*   ei    = (const int*)d_in[3];
  const float* g0    = (const float*)d_in[4];
  const float* b0    = (const float*)d_in[5];
  const float* W1    = (const float*)d_in[6];
  const float* b1    = (const float*)d_in[7];
  const float* g1    = (const float*)d_in[8];
  const float* be1   = (const float*)d_in[9];
  const float* W2    = (const float*)d_in[10];
  const float* b2    = (const float*)d_in[11];
  const float* g2    = (const float*)d_in[12];
  const float* be2   = (const float*)d_in[13];
  const float* W3    = (const float*)d_in[14];
  const float* b3    = (const float*)d_in[15];
  const float* g3    = (const float*)d_in[16];
  const float* be3   = (const float*)d_in[17];
  const float* W4    = (const float*)d_in[18];
  const float* b4    = (const float*)d_in[19];

  char* ws = (char*)d_ws;
  float* c_pa    = (float*)(ws + 0);
  float* w_t     = (float*)(ws + 1024);
  float* c_g     = (float*)(ws + 2048);
  float* c_const = (float*)(ws + 3072);
  float* scal    = (float*)(ws + 4096);
  unsigned long long* adj = (unsigned long long*)(ws + 4608);
  float* wzT = (float*)(ws + 5120);                       // 64 KB
  float* wzZ = (float*)(ws + 70656);                      // 64 KB
  unsigned short* W2Ah = (unsigned short*)(ws + 136192);  // 64 KB
  unsigned short* W2Al = (unsigned short*)(ws + 201728);  // 64 KB
  unsigned short* W3Ah = (unsigned short*)(ws + 267264);  // 16 KB
  unsigned short* W3Al = (unsigned short*)(ws + 283648);  // 16 KB
  unsigned short* W4Ah = (unsigned short*)(ws + 300032);  // 8 KB
  unsigned short* W4Al = (unsigned short*)(ws + 308224);  // 8 KB
  float* st = (float*)(ws + 316416);                      // 400 floats
  unsigned char* nxt  = (unsigned char*)(ws + 318464);    // 2 MB
  unsigned char* cmap = (unsigned char*)(ws + 2415616);   // 16 KB
  int* startz = (int*)(ws + 2432000);                     // 1 KB
  unsigned char* zones = (unsigned char*)(ws + 2433024);  // 32 KB

  k_prep<<<1, 256, 0, stream>>>(pa, g0, b0, W1, b1, c_pa, w_t, c_g, c_const,
                                scal, wzT, wzZ);
  k_prep2<<<1, 128, 0, stream>>>(c_pa, w_t, c_g, c_const, wzT, st);
  k_scal2st<<<1, 64, 0, stream>>>(scal, st);
  k_adj<<<1, 256, 0, stream>>>(ei, adj);
  k_wsplit<<<176, 256, 0, stream>>>(W2, W3, W4, W2Ah, W2Al, W3Ah, W3Al, W4Ah, W4Al);
  k_pass1<<<32768, 256, 0, stream>>>(times, c_pa, w_t, c_g, c_const, wzT, st,
                                     W2Ah, W2Al, W3Ah, W3Al, W4Ah, W4Al,
                                     b2, b3, b4, g1, be1, g2, be2, g3, be3,
                                     adj, nxt);
  k_scan_a<<<256, 64, 0, stream>>>(nxt, cmap);
  k_scan_b<<<1, 64, 0, stream>>>(cmap, startz);
  k_scan_c<<<256, 64, 0, stream>>>(nxt, startz, zones);
  k_pass2m<<<512, 256, 0, stream>>>(times, zones, c_pa, w_t, c_g, c_const,
                                    wzZ, st, W2Ah, W2Al, W3Ah, W3Al, W4Ah, W4Al,
                                    b2, b3, b4, g1, be1, g2, be2, g3, be3,
                                    adj, (float*)d_out);
}

// Round 9
// 784.096 us; speedup vs baseline: 1.6439x; 1.0119x over previous
//
#include <hip/hip_runtime.h>
#include <stdint.h>

typedef __attribute__((ext_vector_type(8))) short bf16x8;
typedef __attribute__((ext_vector_type(4))) float f32x4;
typedef __attribute__((ext_vector_type(4))) unsigned int u32x4;
typedef __attribute__((ext_vector_type(2))) unsigned int u32x2;

#define MFMA(a, b, c) __builtin_amdgcn_mfma_f32_16x16x32_bf16(a, b, c, 0, 0, 0)

__device__ __forceinline__ unsigned short f2b(float x) {
  unsigned u = __float_as_uint(x);
  return (unsigned short)((u + 0x7fffu + ((u >> 16) & 1u)) >> 16);
}
__device__ __forceinline__ float b2f(unsigned short h) {
  return __uint_as_float(((unsigned)h) << 16);
}

// truncation-based Dekker split of two fp32 into packed bf16 hi/lo dwords.
// v_perm_b32 packs the two hi-halves in one op: sel 0x07060302 ->
// [u0.b2,u0.b3,u1.b2,u1.b3] with perm(src0=u1, src1=u0).
struct u2 { unsigned hi, lo; };
__device__ __forceinline__ u2 split2(float h0, float h1) {
  unsigned u0 = __float_as_uint(h0), u1 = __float_as_uint(h1);
  u2 r;
  r.hi = __builtin_amdgcn_perm(u1, u0, 0x07060302u);
  float r0 = h0 - __uint_as_float(u0 & 0xffff0000u);
  float r1 = h1 - __uint_as_float(u1 & 0xffff0000u);
  r.lo = __builtin_amdgcn_perm(__float_as_uint(r1), __float_as_uint(r0), 0x07060302u);
  return r;
}

// scratch swizzle (used by k_pass2m only)
#define SWZ(row, col) ((col) ^ ((((row) >> 2) & 1) << 4) ^ ((((row) >> 3) & 1) << 2))

// ---------------- merged setup kernel ----------------
// phase 1: k_prep (coefficient vectors, wzT/wzZ, scal -> st[384..385])
// phase 2: per-z tables + Gram terms (st[0..383], st[386..399])
// phase 3: adjacency bitmasks

__global__ void k_setup(const float* __restrict__ pa, const float* __restrict__ g0,
                        const float* __restrict__ b0, const float* __restrict__ W1,
                        const float* __restrict__ b1, const int* __restrict__ ei,
                        float* __restrict__ c_pa, float* __restrict__ w_t,
                        float* __restrict__ c_g, float* __restrict__ c_const,
                        float* __restrict__ wzT, float* __restrict__ wzZ,
                        float* __restrict__ st, unsigned long long* __restrict__ adj) {
  int j = threadIdx.x;  // 256
  {
    const float* wr = W1 + j * 97;
    float cg = 0.f, cc = 0.f, cp = 0.f;
    for (int k = 0; k < 97; ++k) { float w = wr[k]; cg += w * g0[k]; cc += w * b0[k]; }
    for (int k = 0; k < 32; ++k) cp += wr[k] * g0[k] * pa[k];
    c_g[j] = cg;
    c_const[j] = cc + b1[j];
    c_pa[j] = cp;
    w_t[j] = wr[32] * g0[32];
    for (int z = 0; z < 64; ++z) {
      float v = wr[33 + z] * g0[33 + z];
      wzT[j * 64 + z] = v;
      wzZ[z * 256 + j] = v;
    }
    if (j == 0) {
      float s = 0.f, q = 0.f;
      for (int k = 0; k < 32; ++k) { float x = pa[k]; s += x; q += x * x; }
      st[384] = s; st[385] = q;
    }
  }
  __syncthreads();
  if (j < 64) {
    int z = j;
    float A = 0.f, Q = 0.f, dpa = 0.f, dwt = 0.f, dcg = 0.f, dcc = 0.f;
    for (int k = 0; k < 256; ++k) {
      float wz = wzT[k * 64 + z];
      A += wz; Q = fmaf(wz, wz, Q);
      dpa = fmaf(c_pa[k], wz, dpa);
      dwt = fmaf(w_t[k], wz, dwt);
      dcg = fmaf(c_g[k], wz, dcg);
      dcc = fmaf(c_const[k], wz, dcc);
    }
    st[z] = A; st[64 + z] = Q; st[128 + z] = dpa;
    st[192 + z] = dwt; st[256 + z] = dcg; st[320 + z] = dcc;
  } else if (j < 128) {
    int lane = j - 64;
    float acc[14];
    #pragma unroll
    for (int m = 0; m < 14; ++m) acc[m] = 0.f;
    for (int k = lane; k < 256; k += 64) {
      float P = c_pa[k], W = w_t[k], G = c_g[k], C = c_const[k];
      acc[0] += P; acc[1] += W; acc[2] += G; acc[3] += C;
      acc[4] = fmaf(P, P, acc[4]); acc[5] = fmaf(P, W, acc[5]);
      acc[6] = fmaf(P, G, acc[6]); acc[7] = fmaf(P, C, acc[7]);
      acc[8] = fmaf(W, W, acc[8]); acc[9] = fmaf(W, G, acc[9]);
      acc[10] = fmaf(W, C, acc[10]); acc[11] = fmaf(G, G, acc[11]);
      acc[12] = fmaf(G, C, acc[12]); acc[13] = fmaf(C, C, acc[13]);
    }
    #pragma unroll
    for (int off = 1; off < 64; off <<= 1) {
      #pragma unroll
      for (int m = 0; m < 14; ++m) acc[m] += __shfl_xor(acc[m], off, 64);
    }
    if (lane == 0) {
      #pragma unroll
      for (int m = 0; m < 14; ++m) st[386 + m] = acc[m];
    }
  }
  // phase 3: adjacency (re-inits stale workspace every call)
  if (j < 64) adj[j] = 1ull << j;
  __syncthreads();
  int u = ei[j] & 63, v = ei[256 + j] & 63;
  atomicOr(&adj[u], 1ull << v);
  atomicOr(&adj[v], 1ull << u);
}

// Pre-split weights into MFMA A-fragment order, bf16 hi/lo (RNE, done once).
__global__ void k_wsplit(const float* __restrict__ W2, const float* __restrict__ W3,
                         const float* __restrict__ W4,
                         unsigned short* __restrict__ W2Ah, unsigned short* __restrict__ W2Al,
                         unsigned short* __restrict__ W3Ah, unsigned short* __restrict__ W3Al,
                         unsigned short* __restrict__ W4Ah, unsigned short* __restrict__ W4Al) {
  int idx = blockIdx.x * 256 + threadIdx.x;
  float w; unsigned short* ph; unsigned short* pl; int o;
  if (idx < 32768) {                       // W2 [128][256]
    int mt = idx >> 12, kt = (idx >> 9) & 7, lane = (idx >> 3) & 63, j = idx & 7;
    int m = mt * 16 + (lane & 15), k = kt * 32 + (lane >> 4) * 8 + j;
    w = W2[m * 256 + k]; ph = W2Ah; pl = W2Al; o = idx;
  } else if (idx < 40960) {                // W3 [64][128]
    int r = idx - 32768;
    int mt = r >> 11, kt = (r >> 9) & 3, lane = (r >> 3) & 63, j = r & 7;
    int m = mt * 16 + (lane & 15), k = kt * 32 + (lane >> 4) * 8 + j;
    w = W3[m * 128 + k]; ph = W3Ah; pl = W3Al; o = r;
  } else if (idx < 45056) {                // W4 [64][64]
    int r = idx - 40960;
    int mt = r >> 10, kt = (r >> 9) & 1, lane = (r >> 3) & 63, j = r & 7;
    int m = mt * 16 + (lane & 15), k = kt * 32 + (lane >> 4) * 8 + j;
    w = W4[m * 64 + k]; ph = W4Ah; pl = W4Al; o = r;
  } else return;
  unsigned short hb = f2b(w);
  ph[o] = hb;
  pl[o] = f2b(w - b2f(hb));
}

// ---------------- pass 1: transition table next[i][z] ----------------
// 16KB frag region (K=64 chunks), shared P/Q LN tables, G/W per-k LN1 fold.
// launch_bounds(256,5): combined VGPR+AGPR cap ~102 (no spill), 5 blocks/CU.

__global__ __launch_bounds__(256, 5) void k_pass1(
    const float* __restrict__ times,
    const float* __restrict__ c_pa, const float* __restrict__ w_t,
    const float* __restrict__ c_g, const float* __restrict__ c_const,
    const float* __restrict__ wzT, const float* __restrict__ st,
    const unsigned short* __restrict__ W2Ah, const unsigned short* __restrict__ W2Al,
    const unsigned short* __restrict__ W3Ah, const unsigned short* __restrict__ W3Al,
    const unsigned short* __restrict__ W4Ah, const unsigned short* __restrict__ W4Al,
    const float* __restrict__ b2, const float* __restrict__ b3,
    const float* __restrict__ b4,
    const float* __restrict__ g1, const float* __restrict__ be1,
    const float* __restrict__ g2, const float* __restrict__ be2,
    const float* __restrict__ g3, const float* __restrict__ be3,
    const unsigned long long* __restrict__ adj,
    unsigned char* __restrict__ nxt) {
  __shared__ __align__(16) char region[16384];   // [2kt][4nt][64][8] hi | lo
  __shared__ float G_lds[256];                   // alpha * g1[k]
  __shared__ float W_lds[256];                   // g1[k] * u[k]
  __shared__ float ps[512];                      // partials; P/Q tables; pk alias

  unsigned short* Bhi = (unsigned short*)region;
  unsigned short* Blo = (unsigned short*)(region + 8192);
  unsigned long long* pk = (unsigned long long*)ps;

  const int tid = threadIdx.x;
  const int lane = tid & 63;          // lane == zone z for producer phases
  const int l15 = lane & 15;
  const int lhi = lane >> 4;
  const int w = __builtin_amdgcn_readfirstlane(tid >> 6);
  const int i = blockIdx.x;

  const float t = times[i];
  const float m0 = (st[384] + t + 1.0f) * (1.0f / 97.0f);
  const float e2 = (st[385] + t * t + 1.0f) * (1.0f / 97.0f);
  const float alpha = 1.0f / sqrtf(e2 - m0 * m0 + 1e-5f);
  const float gma = -m0 * alpha;

  const f32x4 zero4 = {0.f, 0.f, 0.f, 0.f};

  // ---- u(k) once per k + block sums; fold LN1 scale into per-k G/W ----
  {
    int k = tid;
    float g1k = g1[k];
    float u = fmaf(t, w_t[k], c_pa[k]);
    u = fmaf(alpha, u, c_const[k]);
    u = fmaf(gma, c_g[k], u);
    G_lds[k] = alpha * g1k;
    W_lds[k] = g1k * u;
    float su = u, sq = u * u;
    #pragma unroll
    for (int off = 1; off < 64; off <<= 1) {
      su += __shfl_xor(su, off, 64);
      sq += __shfl_xor(sq, off, 64);
    }
    if (lane == 0) { ps[w] = su; ps[256 + w] = sq; }
  }
  __syncthreads();
  float mu1, inv1;
  {
    float U1 = ps[0] + ps[1] + ps[2] + ps[3];
    float Qu = ps[256] + ps[257] + ps[258] + ps[259];
    float A1 = st[lane], Qz = st[64 + lane];
    float dpa = st[128 + lane], dwt = st[192 + lane];
    float dcg = st[256 + lane], dcc = st[320 + lane];
    float s1 = fmaf(alpha, A1, U1);
    float uwz = fmaf(alpha, fmaf(t, dwt, dpa), fmaf(gma, dcg, dcc));
    float s2 = Qu + 2.0f * alpha * uwz + alpha * alpha * Qz;
    mu1 = s1 * (1.0f / 256.0f);
    inv1 = 1.0f / sqrtf(s2 * (1.0f / 256.0f) - mu1 * mu1 + 1e-5f);
  }

  // ---- GEMM1: h2[128][64] = W2 @ h1, K=256 in 4 chunks of 64 ----
  f32x4 acc[2][4];
  #pragma unroll
  for (int a = 0; a < 2; ++a)
    #pragma unroll
    for (int b = 0; b < 4; ++b) acc[a][b] = zero4;

  for (int kc = 0; kc < 4; ++kc) {
    if (kc) __syncthreads();          // previous chunk's MFMA readers done
    // producers: 2 octets per wave: o = w*2+q, k = kc*64 + o*8 + j, z = lane
    // h = max(0, inv1*(G_k*wz + W_k - g1_k*mu1) + be1_k)
    #pragma unroll
    for (int q = 0; q < 2; ++q) {
      int o = w * 2 + q;
      int kb = kc * 64 + o * 8;
      f32x4 G0 = *(const f32x4*)(G_lds + kb);
      f32x4 G1 = *(const f32x4*)(G_lds + kb + 4);
      f32x4 W0 = *(const f32x4*)(W_lds + kb);
      f32x4 W1v = *(const f32x4*)(W_lds + kb + 4);
      float hbuf[8];
      #pragma unroll
      for (int j = 0; j < 8; ++j) {
        int k = kb + j;
        float Gk = (j < 4) ? G0[j] : G1[j - 4];
        float Wk = (j < 4) ? W0[j] : W1v[j - 4];
        float t1 = fmaf(Gk, wzT[k * 64 + lane], Wk);
        float t2 = fmaf(-g1[k], mu1, t1);
        hbuf[j] = fmaxf(fmaf(inv1, t2, be1[k]), 0.f);
      }
      u32x4 vh, vl;
      #pragma unroll
      for (int e = 0; e < 4; ++e) {
        u2 s = split2(hbuf[2 * e], hbuf[2 * e + 1]);
        vh[e] = s.hi; vl[e] = s.lo;
      }
      int slotd = (((o >> 2) * 4 + lhi) * 64 + (o & 3) * 16 + l15) * 4;
      *(u32x4*)((unsigned*)Bhi + slotd) = vh;
      *(u32x4*)((unsigned*)Blo + slotd) = vl;
    }
    __syncthreads();
    // MFMA: wave owns M rows [32w, 32w+32)
    #pragma unroll
    for (int kt = 0; kt < 2; ++kt) {
      int ktg = kc * 2 + kt;
      bf16x8 a0h = *(const bf16x8*)(W2Ah + (((2 * w + 0) * 8 + ktg) * 64 + lane) * 8);
      bf16x8 a0l = *(const bf16x8*)(W2Al + (((2 * w + 0) * 8 + ktg) * 64 + lane) * 8);
      bf16x8 a1h = *(const bf16x8*)(W2Ah + (((2 * w + 1) * 8 + ktg) * 64 + lane) * 8);
      bf16x8 a1l = *(const bf16x8*)(W2Al + (((2 * w + 1) * 8 + ktg) * 64 + lane) * 8);
      #pragma unroll
      for (int nt = 0; nt < 4; ++nt) {
        bf16x8 bh = *(const bf16x8*)(Bhi + ((kt * 4 + nt) * 64 + lane) * 8);
        bf16x8 bl = *(const bf16x8*)(Blo + ((kt * 4 + nt) * 64 + lane) * 8);
        acc[0][nt] = MFMA(a0h, bh, acc[0][nt]);
        acc[0][nt] = MFMA(a0h, bl, acc[0][nt]);
        acc[0][nt] = MFMA(a0l, bh, acc[0][nt]);
        acc[1][nt] = MFMA(a1h, bh, acc[1][nt]);
        acc[1][nt] = MFMA(a1h, bl, acc[1][nt]);
        acc[1][nt] = MFMA(a1l, bh, acc[1][nt]);
      }
    }
  }

  // +b2, LN2 partial sums (per column over 128 rows)
  #pragma unroll
  for (int mti = 0; mti < 2; ++mti) {
    f32x4 bv = *(const f32x4*)(b2 + w * 32 + mti * 16 + lhi * 4);
    #pragma unroll
    for (int nt = 0; nt < 4; ++nt) acc[mti][nt] += bv;
  }
  #pragma unroll
  for (int nt = 0; nt < 4; ++nt) {
    float x1 = 0.f, x2 = 0.f;
    #pragma unroll
    for (int mti = 0; mti < 2; ++mti)
      #pragma unroll
      for (int r = 0; r < 4; ++r) { float v = acc[mti][nt][r]; x1 += v; x2 += v * v; }
    x1 += __shfl_xor(x1, 16, 64); x1 += __shfl_xor(x1, 32, 64);
    x2 += __shfl_xor(x2, 16, 64); x2 += __shfl_xor(x2, 32, 64);
    if (lane < 16) {
      ps[w * 64 + nt * 16 + lane] = x1;
      ps[256 + w * 64 + nt * 16 + lane] = x2;
    }
  }
  __syncthreads();
  // P/Q table for LN2 (wave 0 only; one rsqrt per column)
  if (w == 0) {
    int c = lane;
    float a = ps[c] + ps[64 + c] + ps[128 + c] + ps[192 + c];
    float b = ps[256 + c] + ps[320 + c] + ps[384 + c] + ps[448 + c];
    float mu = a * (1.0f / 128.0f);
    float inv = 1.0f / sqrtf(b * (1.0f / 128.0f) - mu * mu + 1e-5f);
    ps[c] = inv;               // P
    ps[64 + c] = -mu * inv;    // Q
  }
  __syncthreads();

  // ---- GEMM2: h3[64][64] = W3 @ h2, K=128 in 2 chunks of 64 ----
  f32x4 acc2[4];
  #pragma unroll
  for (int b = 0; b < 4; ++b) acc2[b] = zero4;

  for (int kc2 = 0; kc2 < 2; ++kc2) {
    if ((w >> 1) == kc2) {            // waves 2*kc2, 2*kc2+1 own these h2 rows
      f32x4 g2v[2], be2v[2];
      #pragma unroll
      for (int mti = 0; mti < 2; ++mti) {
        g2v[mti]  = *(const f32x4*)(g2  + w * 32 + mti * 16 + lhi * 4);
        be2v[mti] = *(const f32x4*)(be2 + w * 32 + mti * 16 + lhi * 4);
      }
      #pragma unroll
      for (int nt = 0; nt < 4; ++nt) {
        int c = nt * 16 + l15;
        float P = ps[c], Q = ps[64 + c];
        #pragma unroll
        for (int mti = 0; mti < 2; ++mti) {
          float h[4];
          #pragma unroll
          for (int r = 0; r < 4; ++r) {
            float G = g2v[mti][r];
            h[r] = fmaxf(fmaf(acc[mti][nt][r], G * P, fmaf(G, Q, be2v[mti][r])), 0.f);
          }
          u2 s01 = split2(h[0], h[1]);
          u2 s23 = split2(h[2], h[3]);
          int base = (((w - 2 * kc2) * 4 + nt) * 64 +
                      (mti * 2 + (lhi >> 1)) * 16 + l15) * 8 + (lhi & 1) * 4;
          u32x2 vh = {s01.hi, s23.hi};
          u32x2 vl = {s01.lo, s23.lo};
          *(u32x2*)(Bhi + base) = vh;
          *(u32x2*)(Blo + base) = vl;
        }
      }
    }
    __syncthreads();
    #pragma unroll
    for (int kt = 0; kt < 2; ++kt) {
      int ktg = kc2 * 2 + kt;
      bf16x8 ah = *(const bf16x8*)(W3Ah + ((w * 4 + ktg) * 64 + lane) * 8);
      bf16x8 al = *(const bf16x8*)(W3Al + ((w * 4 + ktg) * 64 + lane) * 8);
      #pragma unroll
      for (int nt = 0; nt < 4; ++nt) {
        bf16x8 bh = *(const bf16x8*)(Bhi + ((kt * 4 + nt) * 64 + lane) * 8);
        bf16x8 bl = *(const bf16x8*)(Blo + ((kt * 4 + nt) * 64 + lane) * 8);
        acc2[nt] = MFMA(ah, bh, acc2[nt]);
        acc2[nt] = MFMA(ah, bl, acc2[nt]);
        acc2[nt] = MFMA(al, bh, acc2[nt]);
      }
    }
    __syncthreads();
  }

  // +b3, LN3 partial sums
  {
    f32x4 bv = *(const f32x4*)(b3 + w * 16 + lhi * 4);
    #pragma unroll
    for (int nt = 0; nt < 4; ++nt) acc2[nt] += bv;
  }
  #pragma unroll
  for (int nt = 0; nt < 4; ++nt) {
    float x1 = 0.f, x2 = 0.f;
    #pragma unroll
    for (int r = 0; r < 4; ++r) { float v = acc2[nt][r]; x1 += v; x2 += v * v; }
    x1 += __shfl_xor(x1, 16, 64); x1 += __shfl_xor(x1, 32, 64);
    x2 += __shfl_xor(x2, 16, 64); x2 += __shfl_xor(x2, 32, 64);
    if (lane < 16) {
      ps[w * 64 + nt * 16 + lane] = x1;
      ps[256 + w * 64 + nt * 16 + lane] = x2;
    }
  }
  __syncthreads();
  if (w == 0) {
    int c = lane;
    float a = ps[c] + ps[64 + c] + ps[128 + c] + ps[192 + c];
    float b = ps[256 + c] + ps[320 + c] + ps[384 + c] + ps[448 + c];
    float mu = a * (1.0f / 64.0f);
    float inv = 1.0f / sqrtf(b * (1.0f / 64.0f) - mu * mu + 1e-5f);
    ps[c] = inv;               // P
    ps[64 + c] = -mu * inv;    // Q
  }
  __syncthreads();

  // ---- B3 producers: all waves, direct scatter from acc2 ----
  {
    f32x4 g3v  = *(const f32x4*)(g3  + w * 16 + lhi * 4);
    f32x4 be3v = *(const f32x4*)(be3 + w * 16 + lhi * 4);
    #pragma unroll
    for (int nt = 0; nt < 4; ++nt) {
      int c = nt * 16 + l15;
      float P = ps[c], Q = ps[64 + c];
      float h[4];
      #pragma unroll
      for (int r = 0; r < 4; ++r) {
        float G = g3v[r];
        h[r] = fmaxf(fmaf(acc2[nt][r], G * P, fmaf(G, Q, be3v[r])), 0.f);
      }
      u2 s01 = split2(h[0], h[1]);
      u2 s23 = split2(h[2], h[3]);
      int base = (((w >> 1) * 4 + nt) * 64 +
                  ((w & 1) * 2 + (lhi >> 1)) * 16 + l15) * 8 + (lhi & 1) * 4;
      u32x2 vh = {s01.hi, s23.hi};
      u32x2 vl = {s01.lo, s23.lo};
      *(u32x2*)(Bhi + base) = vh;
      *(u32x2*)(Blo + base) = vl;
    }
  }
  __syncthreads();

  // ---- GEMM3: raw[64][64] = W4 @ h3 ----
  f32x4 acc3[4];
  #pragma unroll
  for (int b = 0; b < 4; ++b) acc3[b] = zero4;
  #pragma unroll
  for (int kt = 0; kt < 2; ++kt) {
    bf16x8 ah = *(const bf16x8*)(W4Ah + ((w * 2 + kt) * 64 + lane) * 8);
    bf16x8 al = *(const bf16x8*)(W4Al + ((w * 2 + kt) * 64 + lane) * 8);
    #pragma unroll
    for (int nt = 0; nt < 4; ++nt) {
      bf16x8 bh = *(const bf16x8*)(Bhi + ((kt * 4 + nt) * 64 + lane) * 8);
      bf16x8 bl = *(const bf16x8*)(Blo + ((kt * 4 + nt) * 64 + lane) * 8);
      acc3[nt] = MFMA(ah, bh, acc3[nt]);
      acc3[nt] = MFMA(ah, bl, acc3[nt]);
      acc3[nt] = MFMA(al, bh, acc3[nt]);
    }
  }
  f32x4 b4v = *(const f32x4*)(b4 + w * 16 + lhi * 4);
  unsigned long long kbest[4];
  #pragma unroll
  for (int nt = 0; nt < 4; ++nt) {
    unsigned long long am = adj[nt * 16 + l15];
    unsigned long long kb = 0ull;
    #pragma unroll
    for (int r = 0; r < 4; ++r) {
      int o = w * 16 + lhi * 4 + r;
      float raw = acc3[nt][r] + b4v[r];
      float val = ((am >> o) & 1ull) ? raw : -__builtin_huge_valf();
      unsigned u = __float_as_uint(val);
      u = (u & 0x80000000u) ? ~u : (u | 0x80000000u);
      unsigned long long key = ((unsigned long long)u << 6) | (unsigned long long)(63 - o);
      if (key > kb) kb = key;
    }
    unsigned long long oth = __shfl_xor(kb, 16, 64); if (oth > kb) kb = oth;
    oth = __shfl_xor(kb, 32, 64); if (oth > kb) kb = oth;
    kbest[nt] = kb;
  }
  if (lane < 16) {
    #pragma unroll
    for (int nt = 0; nt < 4; ++nt) pk[w * 64 + nt * 16 + lane] = kbest[nt];
  }
  __syncthreads();
  if (tid < 64) {
    unsigned long long k0 = pk[tid], k1 = pk[64 + tid];
    unsigned long long k2 = pk[128 + tid], k3 = pk[192 + tid];
    unsigned long long a = k0 > k1 ? k0 : k1;
    unsigned long long b = k2 > k3 ? k2 : k3;
    unsigned long long bb = a > b ? a : b;
    nxt[(size_t)i * 64 + tid] = (unsigned char)(63u - (unsigned)(bb & 63ull));
  }
}

// ---------------- trajectory via parallel map-composition scan ----------------

__global__ void k_scan_a(const unsigned char* __restrict__ nxt,
                         unsigned char* __restrict__ cmap) {
  int c = blockIdx.x, lane = threadIdx.x;
  int g = lane;
  const unsigned char* p = nxt + (size_t)c * 128 * 64;
  for (int s = 0; s < 128; ++s) {
    int sig = p[s * 64 + lane];
    g = __shfl(sig, g, 64);
  }
  cmap[c * 64 + lane] = (unsigned char)g;
}

__global__ void k_scan_b(const unsigned char* __restrict__ cmap,
                         int* __restrict__ startz) {
  int lane = threadIdx.x;
  int cur = 0;
  for (int c = 0; c < 256; ++c) {
    if (lane == 0) startz[c] = cur;
    int row = cmap[c * 64 + lane];
    cur = __shfl(row, cur, 64);
  }
}

__global__ void k_scan_c(const unsigned char* __restrict__ nxt,
                         const int* __restrict__ startz,
                         unsigned char* __restrict__ zones) {
  int c = blockIdx.x, lane = threadIdx.x;
  int cur = startz[c];
  const unsigned char* p = nxt + (size_t)c * 128 * 64;
  for (int s = 0; s < 128; ++s) {
    if (lane == 0) zones[c * 128 + s] = (unsigned char)cur;
    int row = p[s * 64 + lane];
    cur = __shfl(row, cur, 64);
  }
}

// ---------------- pass 2m: logits for actual zones, 64 timesteps/block ----------------

__global__ __launch_bounds__(256, 2) void k_pass2m(
    const float* __restrict__ times, const unsigned char* __restrict__ zones,
    const float* __restrict__ c_pa, const float* __restrict__ w_t,
    const float* __restrict__ c_g, const float* __restrict__ c_const,
    const float* __restrict__ wzZ, const float* __restrict__ st,
    const unsigned short* __restrict__ W2Ah, const unsigned short* __restrict__ W2Al,
    const unsigned short* __restrict__ W3Ah, const unsigned short* __restrict__ W3Al,
    const unsigned short* __restrict__ W4Ah, const unsigned short* __restrict__ W4Al,
    const float* __restrict__ b2, const float* __restrict__ b3,
    const float* __restrict__ b4,
    const float* __restrict__ g1, const float* __restrict__ be1,
    const float* __restrict__ g2, const float* __restrict__ be2,
    const float* __restrict__ g3, const float* __restrict__ be3,
    const unsigned long long* __restrict__ adj,
    float* __restrict__ out) {
  __shared__ __align__(16) char region[32768];
  __shared__ float ps1[256], ps2[256];
  __shared__ unsigned long long am_lds[64];

  unsigned short* B1hi = (unsigned short*)region;
  unsigned short* B1lo = (unsigned short*)(region + 16384);
  float* h2p = (float*)region;
  unsigned short* B2hi = (unsigned short*)region;
  unsigned short* B2lo = (unsigned short*)(region + 16384);
  float* h3p = (float*)region;
  unsigned short* B3hi = (unsigned short*)(region + 16384);
  unsigned short* B3lo = (unsigned short*)(region + 24576);
  float* outT = (float*)region;

  const int tid = threadIdx.x;
  const int lane = tid & 63;
  const int l15 = lane & 15;
  const int lhi = lane >> 4;
  const int w = __builtin_amdgcn_readfirstlane(tid >> 6);
  const int i0 = blockIdx.x * 64;

  const float t = times[i0 + lane];
  const int z = zones[i0 + lane];
  const int zrow = z << 8;
  if (tid < 64) am_lds[tid] = adj[zones[i0 + tid]];

  const float m0 = (st[384] + t + 1.0f) * (1.0f / 97.0f);
  const float e2 = (st[385] + t * t + 1.0f) * (1.0f / 97.0f);
  const float a0 = 1.0f / sqrtf(e2 - m0 * m0 + 1e-5f);
  const float a1 = a0 * t;
  const float a2 = -m0 * a0;

  float mu1, inv1;
  {
    float SP = st[386], SW = st[387], SG = st[388], SC = st[389];
    float PP = st[390], PW = st[391], PG = st[392], PC = st[393];
    float WW = st[394], WG = st[395], WC = st[396];
    float GG = st[397], GC = st[398], CC = st[399];
    float U1 = a0 * SP + a1 * SW + a2 * SG + SC;
    float s1 = fmaf(a0, st[z], U1);
    float Qu = a0 * a0 * PP + a1 * a1 * WW + a2 * a2 * GG + CC
             + 2.0f * (a0 * a1 * PW + a0 * a2 * PG + a0 * PC
                       + a1 * a2 * WG + a1 * WC + a2 * GC);
    float uwz = a0 * st[128 + z] + a1 * st[192 + z] + a2 * st[256 + z] + st[320 + z];
    float s2 = Qu + 2.0f * a0 * uwz + a0 * a0 * st[64 + z];
    mu1 = s1 * (1.0f / 256.0f);
    inv1 = 1.0f / sqrtf(s2 * (1.0f / 256.0f) - mu1 * mu1 + 1e-5f);
  }

  const f32x4 zero4 = {0.f, 0.f, 0.f, 0.f};
  f32x4 acc[2][4];
  #pragma unroll
  for (int a = 0; a < 2; ++a)
    #pragma unroll
    for (int b = 0; b < 4; ++b) acc[a][b] = zero4;

  for (int kc = 0; kc < 2; ++kc) {
    if (kc) __syncthreads();
    #pragma unroll
    for (int q = 0; q < 4; ++q) {
      int kb = kc * 128 + w * 32 + q * 8;
      float hbuf[8];
      #pragma unroll
      for (int j = 0; j < 8; ++j) {
        int k = kb + j;
        float u = fmaf(a0, c_pa[k], fmaf(a1, w_t[k], fmaf(a2, c_g[k], c_const[k])));
        float p = fmaf(a0, wzZ[zrow + k], u);
        float gi = g1[k] * inv1;
        float bb = fmaf(-mu1, gi, be1[k]);
        hbuf[j] = fmaxf(fmaf(p, gi, bb), 0.f);
      }
      u32x4 vh, vl;
      #pragma unroll
      for (int e = 0; e < 4; ++e) {
        u2 s = split2(hbuf[2 * e], hbuf[2 * e + 1]);
        vh[e] = s.hi; vl[e] = s.lo;
      }
      int slotd = ((w * 4 + lhi) * 64 + q * 16 + l15) * 4;
      *(u32x4*)((unsigned*)B1hi + slotd) = vh;
      *(u32x4*)((unsigned*)B1lo + slotd) = vl;
    }
    __syncthreads();
    for (int kt = 0; kt < 4; ++kt) {
      int ktg = kc * 4 + kt;
      bf16x8 a0h = *(const bf16x8*)(W2Ah + (((2 * w + 0) * 8 + ktg) * 64 + lane) * 8);
      bf16x8 a0l = *(const bf16x8*)(W2Al + (((2 * w + 0) * 8 + ktg) * 64 + lane) * 8);
      bf16x8 a1h = *(const bf16x8*)(W2Ah + (((2 * w + 1) * 8 + ktg) * 64 + lane) * 8);
      bf16x8 a1l = *(const bf16x8*)(W2Al + (((2 * w + 1) * 8 + ktg) * 64 + lane) * 8);
      #pragma unroll
      for (int nt = 0; nt < 4; ++nt) {
        bf16x8 bh = *(const bf16x8*)(B1hi + ((kt * 4 + nt) * 64 + lane) * 8);
        bf16x8 bl = *(const bf16x8*)(B1lo + ((kt * 4 + nt) * 64 + lane) * 8);
        acc[0][nt] = MFMA(a0h, bh, acc[0][nt]);
        acc[0][nt] = MFMA(a0h, bl, acc[0][nt]);
        acc[0][nt] = MFMA(a0l, bh, acc[0][nt]);
        acc[1][nt] = MFMA(a1h, bh, acc[1][nt]);
        acc[1][nt] = MFMA(a1h, bl, acc[1][nt]);
        acc[1][nt] = MFMA(a1l, bh, acc[1][nt]);
      }
    }
  }
  #pragma unroll
  for (int mti = 0; mti < 2; ++mti) {
    f32x4 bv = *(const f32x4*)(b2 + w * 32 + mti * 16 + lhi * 4);
    #pragma unroll
    for (int nt = 0; nt < 4; ++nt) acc[mti][nt] += bv;
  }
  {
    float sa[4], sb[4];
    #pragma unroll
    for (int nt = 0; nt < 4; ++nt) {
      float x1 = 0.f, x2 = 0.f;
      #pragma unroll
      for (int mti = 0; mti < 2; ++mti)
        #pragma unroll
        for (int r = 0; r < 4; ++r) { float v = acc[mti][nt][r]; x1 += v; x2 += v * v; }
      x1 += __shfl_xor(x1, 16, 64); x1 += __shfl_xor(x1, 32, 64);
      x2 += __shfl_xor(x2, 16, 64); x2 += __shfl_xor(x2, 32, 64);
      sa[nt] = x1; sb[nt] = x2;
    }
    if (lane < 16) {
      #pragma unroll
      for (int nt = 0; nt < 4; ++nt) {
        ps1[w * 64 + nt * 16 + lane] = sa[nt];
        ps2[w * 64 + nt * 16 + lane] = sb[nt];
      }
    }
  }
  __syncthreads();
  #pragma unroll
  for (int mti = 0; mti < 2; ++mti)
    #pragma unroll
    for (int nt = 0; nt < 4; ++nt)
      #pragma unroll
      for (int r = 0; r < 4; ++r) {
        int row = w * 32 + mti * 16 + lhi * 4 + r;
        h2p[row * 64 + SWZ(row, nt * 16 + l15)] = acc[mti][nt][r];
      }
  __syncthreads();

  float mu2, inv2;
  {
    float a = ps1[lane] + ps1[64 + lane] + ps1[128 + lane] + ps1[192 + lane];
    float b = ps2[lane] + ps2[64 + lane] + ps2[128 + lane] + ps2[192 + lane];
    mu2 = a * (1.0f / 128.0f);
    inv2 = 1.0f / sqrtf(b * (1.0f / 128.0f) - mu2 * mu2 + 1e-5f);
  }
  float hv[32];
  #pragma unroll
  for (int mi = 0; mi < 32; ++mi) {
    int row = w * 32 + mi;
    hv[mi] = h2p[row * 64 + SWZ(row, lane)];
  }
  __syncthreads();
  #pragma unroll
  for (int q = 0; q < 4; ++q) {
    float hbuf[8];
    #pragma unroll
    for (int j = 0; j < 8; ++j) {
      int mi = q * 8 + j, mm = w * 32 + mi;
      float gi = g2[mm] * inv2;
      float bb = fmaf(-mu2, gi, be2[mm]);
      hbuf[j] = fmaxf(fmaf(hv[mi], gi, bb), 0.f);
    }
    u32x4 vh, vl;
    #pragma unroll
    for (int e = 0; e < 4; ++e) {
      u2 s = split2(hbuf[2 * e], hbuf[2 * e + 1]);
      vh[e] = s.hi; vl[e] = s.lo;
    }
    int slotd = ((w * 4 + lhi) * 64 + q * 16 + l15) * 4;
    *(u32x4*)((unsigned*)B2hi + slotd) = vh;
    *(u32x4*)((unsigned*)B2lo + slotd) = vl;
  }
  __syncthreads();

  f32x4 acc2[4];
  #pragma unroll
  for (int b = 0; b < 4; ++b) acc2[b] = zero4;
  for (int kt = 0; kt < 4; ++kt) {
    bf16x8 ah = *(const bf16x8*)(W3Ah + ((w * 4 + kt) * 64 + lane) * 8);
    bf16x8 al = *(const bf16x8*)(W3Al + ((w * 4 + kt) * 64 + lane) * 8);
    #pragma unroll
    for (int nt = 0; nt < 4; ++nt) {
      bf16x8 bh = *(const bf16x8*)(B2hi + ((kt * 4 + nt) * 64 + lane) * 8);
      bf16x8 bl = *(const bf16x8*)(B2lo + ((kt * 4 + nt) * 64 + lane) * 8);
      acc2[nt] = MFMA(ah, bh, acc2[nt]);
      acc2[nt] = MFMA(ah, bl, acc2[nt]);
      acc2[nt] = MFMA(al, bh, acc2[nt]);
    }
  }
  {
    f32x4 bv = *(const f32x4*)(b3 + w * 16 + lhi * 4);
    #pragma unroll
    for (int nt = 0; nt < 4; ++nt) acc2[nt] += bv;
  }
  {
    float sa[4], sb[4];
    #pragma unroll
    for (int nt = 0; nt < 4; ++nt) {
      float x1 = 0.f, x2 = 0.f;
      #pragma unroll
      for (int r = 0; r < 4; ++r) { float v = acc2[nt][r]; x1 += v; x2 += v * v; }
      x1 += __shfl_xor(x1, 16, 64); x1 += __shfl_xor(x1, 32, 64);
      x2 += __shfl_xor(x2, 16, 64); x2 += __shfl_xor(x2, 32, 64);
      sa[nt] = x1; sb[nt] = x2;
    }
    if (lane < 16) {
      #pragma unroll
      for (int nt = 0; nt < 4; ++nt) {
        ps1[w * 64 + nt * 16 + lane] = sa[nt];
        ps2[w * 64 + nt * 16 + lane] = sb[nt];
      }
    }
  }
  __syncthreads();
  #pragma unroll
  for (int nt = 0; nt < 4; ++nt)
    #pragma unroll
    for (int r = 0; r < 4; ++r) {
      int row = w * 16 + lhi * 4 + r;
      h3p[row * 64 + SWZ(row, nt * 16 + l15)] = acc2[nt][r];
    }
  __syncthreads();

  float mu3, inv3;
  {
    float a = ps1[lane] + ps1[64 + lane] + ps1[128 + lane] + ps1[192 + lane];
    float b = ps2[lane] + ps2[64 + lane] + ps2[128 + lane] + ps2[192 + lane];
    mu3 = a * (1.0f / 64.0f);
    inv3 = 1.0f / sqrtf(b * (1.0f / 64.0f) - mu3 * mu3 + 1e-5f);
  }
  #pragma unroll
  for (int q = 0; q < 2; ++q) {
    int o = w * 2 + q;
    float hbuf[8];
    #pragma unroll
    for (int j = 0; j < 8; ++j) {
      int mm = o * 8 + j;
      float v = h3p[mm * 64 + SWZ(mm, lane)];
      float gi = g3[mm] * inv3;
      float bb = fmaf(-mu3, gi, be3[mm]);
      hbuf[j] = fmaxf(fmaf(v, gi, bb), 0.f);
    }
    u32x4 vh, vl;
    #pragma unroll
    for (int e = 0; e < 4; ++e) {
      u2 s = split2(hbuf[2 * e], hbuf[2 * e + 1]);
      vh[e] = s.hi; vl[e] = s.lo;
    }
    int slotd = (((o >> 2) * 4 + lhi) * 64 + (o & 3) * 16 + l15) * 4;
    *(u32x4*)((unsigned*)B3hi + slotd) = vh;
    *(u32x4*)((unsigned*)B3lo + slotd) = vl;
  }
  __syncthreads();

  f32x4 acc3[4];
  #pragma unroll
  for (int b = 0; b < 4; ++b) acc3[b] = zero4;
  for (int kt = 0; kt < 2; ++kt) {
    bf16x8 ah = *(const bf16x8*)(W4Ah + ((w * 2 + kt) * 64 + lane) * 8);
    bf16x8 al = *(const bf16x8*)(W4Al + ((w * 2 + kt) * 64 + lane) * 8);
    #pragma unroll
    for (int nt = 0; nt < 4; ++nt) {
      bf16x8 bh = *(const bf16x8*)(B3hi + ((kt * 4 + nt) * 64 + lane) * 8);
      bf16x8 bl = *(const bf16x8*)(B3lo + ((kt * 4 + nt) * 64 + lane) * 8);
      acc3[nt] = MFMA(ah, bh, acc3[nt]);
      acc3[nt] = MFMA(ah, bl, acc3[nt]);
      acc3[nt] = MFMA(al, bh, acc3[nt]);
    }
  }
  f32x4 b4v = *(const f32x4*)(b4 + w * 16 + lhi * 4);
  #pragma unroll
  for (int nt = 0; nt < 4; ++nt) {
    unsigned long long am = am_lds[nt * 16 + l15];
    #pragma unroll
    for (int r = 0; r < 4; ++r) {
      int o = w * 16 + lhi * 4 + r;
      float raw = acc3[nt][r] + b4v[r];
      float predv = ((am >> o) & 1ull) ? raw : -50.0f;
      int b = nt * 16 + l15;
      outT[b * 64 + SWZ(b, o)] = predv;
    }
  }
  __syncthreads();
  {
    int b = tid >> 2, cb = (tid & 3) * 16;
    size_t gbase = ((size_t)(i0 + b)) * 64 + cb;
    #pragma unroll
    for (int c4 = 0; c4 < 4; ++c4) {
      int col = cb + c4 * 4;
      f32x4 v = *(const f32x4*)(outT + b * 64 + SWZ(b, col));
      *(f32x4*)(out + gbase + c4 * 4) = v;
    }
  }
}

// ---------------- launch ----------------

extern "C" void kernel_launch(void* const* d_in, const int* in_sizes, int n_in,
                              void* d_out, int out_size, void* d_ws, size_t ws_size,
                              hipStream_t stream) {
  const float* pa    = (const float*)d_in[0];
  const float* times = (const float*)d_in[1];
  const int*   ei    = (const int*)d_in[3];
  const float* g0    = (const float*)d_in[4];
  const float* b0    = (const float*)d_in[5];
  const float* W1    = (const float*)d_in[6];
  const float* b1    = (const float*)d_in[7];
  const float* g1    = (const float*)d_in[8];
  const float* be1   = (const float*)d_in[9];
  const float* W2    = (const float*)d_in[10];
  const float* b2    = (const float*)d_in[11];
  const float* g2    = (const float*)d_in[12];
  const float* be2   = (const float*)d_in[13];
  const float* W3    = (const float*)d_in[14];
  const float* b3    = (const float*)d_in[15];
  const float* g3    = (const float*)d_in[16];
  const float* be3   = (const float*)d_in[17];
  const float* W4    = (const float*)d_in[18];
  const float* b4    = (const float*)d_in[19];

  char* ws = (char*)d_ws;
  float* c_pa    = (float*)(ws + 0);
  float* w_t     = (float*)(ws + 1024);
  float* c_g     = (float*)(ws + 2048);
  float* c_const = (float*)(ws + 3072);
  unsigned long long* adj = (unsigned long long*)(ws + 4608);
  float* wzT = (float*)(ws + 5120);                       // 64 KB
  float* wzZ = (float*)(ws + 70656);                      // 64 KB
  unsigned short* W2Ah = (unsigned short*)(ws + 136192);  // 64 KB
  unsigned short* W2Al = (unsigned short*)(ws + 201728);  // 64 KB
  unsigned short* W3Ah = (unsigned short*)(ws + 267264);  // 16 KB
  unsigned short* W3Al = (unsigned short*)(ws + 283648);  // 16 KB
  unsigned short* W4Ah = (unsigned short*)(ws + 300032);  // 8 KB
  unsigned short* W4Al = (unsigned short*)(ws + 308224);  // 8 KB
  float* st = (float*)(ws + 316416);                      // 400 floats
  unsigned char* nxt  = (unsigned char*)(ws + 318464);    // 2 MB
  unsigned char* cmap = (unsigned char*)(ws + 2415616);   // 16 KB
  int* startz = (int*)(ws + 2432000);                     // 1 KB
  unsigned char* zones = (unsigned char*)(ws + 2433024);  // 32 KB

  k_setup<<<1, 256, 0, stream>>>(pa, g0, b0, W1, b1, ei, c_pa, w_t, c_g, c_const,
                                 wzT, wzZ, st, adj);
  k_wsplit<<<176, 256, 0, stream>>>(W2, W3, W4, W2Ah, W2Al, W3Ah, W3Al, W4Ah, W4Al);
  k_pass1<<<32768, 256, 0, stream>>>(times, c_pa, w_t, c_g, c_const, wzT, st,
                                     W2Ah, W2Al, W3Ah, W3Al, W4Ah, W4Al,
                                     b2, b3, b4, g1, be1, g2, be2, g3, be3,
                                     adj, nxt);
  k_scan_a<<<256, 64, 0, stream>>>(nxt, cmap);
  k_scan_b<<<1, 64, 0, stream>>>(cmap, startz);
  k_scan_c<<<256, 64, 0, stream>>>(nxt, startz, zones);
  k_pass2m<<<512, 256, 0, stream>>>(times, zones, c_pa, w_t, c_g, c_const,
                                    wzZ, st, W2Ah, W2Al, W3Ah, W3Al, W4Ah, W4Al,
                                    b2, b3, b4, g1, be1, g2, be2, g3, be3,
                                    adj, (float*)d_out);
}

// Round 10
// 771.161 us; speedup vs baseline: 1.6715x; 1.0168x over previous
//
#include <hip/hip_runtime.h>
#include <stdint.h>

typedef __attribute__((ext_vector_type(8))) short bf16x8;
typedef __attribute__((ext_vector_type(4))) float f32x4;
typedef __attribute__((ext_vector_type(2))) float f32x2;
typedef __attribute__((ext_vector_type(4))) unsigned int u32x4;
typedef __attribute__((ext_vector_type(2))) unsigned int u32x2;

#define MFMA(a, b, c) __builtin_amdgcn_mfma_f32_16x16x32_bf16(a, b, c, 0, 0, 0)

__device__ __forceinline__ unsigned short f2b(float x) {
  unsigned u = __float_as_uint(x);
  return (unsigned short)((u + 0x7fffu + ((u >> 16) & 1u)) >> 16);
}
__device__ __forceinline__ float b2f(unsigned short h) {
  return __uint_as_float(((unsigned)h) << 16);
}
__device__ __forceinline__ f32x2 pk2(float a, float b) {
  f32x2 r; r.x = a; r.y = b; return r;
}

// truncation-based Dekker split of a float2 into packed bf16 hi/lo dwords.
// v_perm_b32 packs the two hi-halves in one op; residual sub is packed-f32.
struct u2 { unsigned hi, lo; };
__device__ __forceinline__ u2 split2v(f32x2 h) {
  unsigned u0 = __float_as_uint(h.x), u1 = __float_as_uint(h.y);
  u2 r;
  r.hi = __builtin_amdgcn_perm(u1, u0, 0x07060302u);
  f32x2 tr = pk2(__uint_as_float(u0 & 0xffff0000u), __uint_as_float(u1 & 0xffff0000u));
  f32x2 res = h - tr;                     // v_pk_add_f32 with neg
  r.lo = __builtin_amdgcn_perm(__float_as_uint(res.y), __float_as_uint(res.x), 0x07060302u);
  return r;
}
__device__ __forceinline__ u2 split2(float h0, float h1) { return split2v(pk2(h0, h1)); }

// scratch swizzle (used by k_pass2m only)
#define SWZ(row, col) ((col) ^ ((((row) >> 2) & 1) << 4) ^ ((((row) >> 3) & 1) << 2))

// ---------------- merged setup kernel ----------------

__global__ void k_setup(const float* __restrict__ pa, const float* __restrict__ g0,
                        const float* __restrict__ b0, const float* __restrict__ W1,
                        const float* __restrict__ b1, const int* __restrict__ ei,
                        float* __restrict__ c_pa, float* __restrict__ w_t,
                        float* __restrict__ c_g, float* __restrict__ c_const,
                        float* __restrict__ wzT, float* __restrict__ wzZ,
                        float* __restrict__ st, unsigned long long* __restrict__ adj) {
  int j = threadIdx.x;  // 256
  {
    const float* wr = W1 + j * 97;
    float cg = 0.f, cc = 0.f, cp = 0.f;
    for (int k = 0; k < 97; ++k) { float w = wr[k]; cg += w * g0[k]; cc += w * b0[k]; }
    for (int k = 0; k < 32; ++k) cp += wr[k] * g0[k] * pa[k];
    c_g[j] = cg;
    c_const[j] = cc + b1[j];
    c_pa[j] = cp;
    w_t[j] = wr[32] * g0[32];
    for (int z = 0; z < 64; ++z) {
      float v = wr[33 + z] * g0[33 + z];
      wzT[j * 64 + z] = v;
      wzZ[z * 256 + j] = v;
    }
    if (j == 0) {
      float s = 0.f, q = 0.f;
      for (int k = 0; k < 32; ++k) { float x = pa[k]; s += x; q += x * x; }
      st[384] = s; st[385] = q;
    }
  }
  __syncthreads();
  if (j < 64) {
    int z = j;
    float A = 0.f, Q = 0.f, dpa = 0.f, dwt = 0.f, dcg = 0.f, dcc = 0.f;
    for (int k = 0; k < 256; ++k) {
      float wz = wzT[k * 64 + z];
      A += wz; Q = fmaf(wz, wz, Q);
      dpa = fmaf(c_pa[k], wz, dpa);
      dwt = fmaf(w_t[k], wz, dwt);
      dcg = fmaf(c_g[k], wz, dcg);
      dcc = fmaf(c_const[k], wz, dcc);
    }
    st[z] = A; st[64 + z] = Q; st[128 + z] = dpa;
    st[192 + z] = dwt; st[256 + z] = dcg; st[320 + z] = dcc;
  } else if (j < 128) {
    int lane = j - 64;
    float acc[14];
    #pragma unroll
    for (int m = 0; m < 14; ++m) acc[m] = 0.f;
    for (int k = lane; k < 256; k += 64) {
      float P = c_pa[k], W = w_t[k], G = c_g[k], C = c_const[k];
      acc[0] += P; acc[1] += W; acc[2] += G; acc[3] += C;
      acc[4] = fmaf(P, P, acc[4]); acc[5] = fmaf(P, W, acc[5]);
      acc[6] = fmaf(P, G, acc[6]); acc[7] = fmaf(P, C, acc[7]);
      acc[8] = fmaf(W, W, acc[8]); acc[9] = fmaf(W, G, acc[9]);
      acc[10] = fmaf(W, C, acc[10]); acc[11] = fmaf(G, G, acc[11]);
      acc[12] = fmaf(G, C, acc[12]); acc[13] = fmaf(C, C, acc[13]);
    }
    #pragma unroll
    for (int off = 1; off < 64; off <<= 1) {
      #pragma unroll
      for (int m = 0; m < 14; ++m) acc[m] += __shfl_xor(acc[m], off, 64);
    }
    if (lane == 0) {
      #pragma unroll
      for (int m = 0; m < 14; ++m) st[386 + m] = acc[m];
    }
  }
  if (j < 64) adj[j] = 1ull << j;
  __syncthreads();
  int u = ei[j] & 63, v = ei[256 + j] & 63;
  atomicOr(&adj[u], 1ull << v);
  atomicOr(&adj[v], 1ull << u);
}

// Pre-split weights into MFMA A-fragment order, bf16 hi/lo (RNE, done once).
__global__ void k_wsplit(const float* __restrict__ W2, const float* __restrict__ W3,
                         const float* __restrict__ W4,
                         unsigned short* __restrict__ W2Ah, unsigned short* __restrict__ W2Al,
                         unsigned short* __restrict__ W3Ah, unsigned short* __restrict__ W3Al,
                         unsigned short* __restrict__ W4Ah, unsigned short* __restrict__ W4Al) {
  int idx = blockIdx.x * 256 + threadIdx.x;
  float w; unsigned short* ph; unsigned short* pl; int o;
  if (idx < 32768) {                       // W2 [128][256]
    int mt = idx >> 12, kt = (idx >> 9) & 7, lane = (idx >> 3) & 63, j = idx & 7;
    int m = mt * 16 + (lane & 15), k = kt * 32 + (lane >> 4) * 8 + j;
    w = W2[m * 256 + k]; ph = W2Ah; pl = W2Al; o = idx;
  } else if (idx < 40960) {                // W3 [64][128]
    int r = idx - 32768;
    int mt = r >> 11, kt = (r >> 9) & 3, lane = (r >> 3) & 63, j = r & 7;
    int m = mt * 16 + (lane & 15), k = kt * 32 + (lane >> 4) * 8 + j;
    w = W3[m * 128 + k]; ph = W3Ah; pl = W3Al; o = r;
  } else if (idx < 45056) {                // W4 [64][64]
    int r = idx - 40960;
    int mt = r >> 10, kt = (r >> 9) & 1, lane = (r >> 3) & 63, j = r & 7;
    int m = mt * 16 + (lane & 15), k = kt * 32 + (lane >> 4) * 8 + j;
    w = W4[m * 64 + k]; ph = W4Ah; pl = W4Al; o = r;
  } else return;
  unsigned short hb = f2b(w);
  ph[o] = hb;
  pl[o] = f2b(w - b2f(hb));
}

// ---------------- pass 1: transition table next[i][z] ----------------
// A/B affine refold for LN1 producer (2 VALU/elem), packed-f32 math throughout.

__global__ __launch_bounds__(256, 5) void k_pass1(
    const float* __restrict__ times,
    const float* __restrict__ c_pa, const float* __restrict__ w_t,
    const float* __restrict__ c_g, const float* __restrict__ c_const,
    const float* __restrict__ wzT, const float* __restrict__ st,
    const unsigned short* __restrict__ W2Ah, const unsigned short* __restrict__ W2Al,
    const unsigned short* __restrict__ W3Ah, const unsigned short* __restrict__ W3Al,
    const unsigned short* __restrict__ W4Ah, const unsigned short* __restrict__ W4Al,
    const float* __restrict__ b2, const float* __restrict__ b3,
    const float* __restrict__ b4,
    const float* __restrict__ g1, const float* __restrict__ be1,
    const float* __restrict__ g2, const float* __restrict__ be2,
    const float* __restrict__ g3, const float* __restrict__ be3,
    const unsigned long long* __restrict__ adj,
    unsigned char* __restrict__ nxt) {
  __shared__ __align__(16) char region[16384];   // [2kt][4nt][64][8] hi | lo
  __shared__ float A_lds[256];                   // LN1 affine: h=relu(A*wz+B)
  __shared__ float B_lds[256];
  __shared__ float ps[512];                      // partials; P/Q tables; pk alias

  unsigned short* Bhi = (unsigned short*)region;
  unsigned short* Blo = (unsigned short*)(region + 8192);
  unsigned long long* pk = (unsigned long long*)ps;

  const int tid = threadIdx.x;
  const int lane = tid & 63;          // lane == zone z for producer phases
  const int l15 = lane & 15;
  const int lhi = lane >> 4;
  const int w = __builtin_amdgcn_readfirstlane(tid >> 6);
  const int i = blockIdx.x;

  const float t = times[i];
  const float m0 = (st[384] + t + 1.0f) * (1.0f / 97.0f);
  const float e2 = (st[385] + t * t + 1.0f) * (1.0f / 97.0f);
  const float alpha = 1.0f / sqrtf(e2 - m0 * m0 + 1e-5f);
  const float gma = -m0 * alpha;

  const f32x4 zero4 = {0.f, 0.f, 0.f, 0.f};
  const f32x2 zero2 = {0.f, 0.f};

  // ---- u(k) once per k + block sums ----
  float u_k, g1_k;
  {
    int k = tid;
    g1_k = g1[k];
    float u = fmaf(t, w_t[k], c_pa[k]);
    u = fmaf(alpha, u, c_const[k]);
    u = fmaf(gma, c_g[k], u);
    u_k = u;
    float su = u, sq = u * u;
    #pragma unroll
    for (int off = 1; off < 64; off <<= 1) {
      su += __shfl_xor(su, off, 64);
      sq += __shfl_xor(sq, off, 64);
    }
    if (lane == 0) { ps[w] = su; ps[256 + w] = sq; }
  }
  __syncthreads();
  float mu1, inv1;
  {
    float U1 = ps[0] + ps[1] + ps[2] + ps[3];
    float Qu = ps[256] + ps[257] + ps[258] + ps[259];
    float A1 = st[lane], Qz = st[64 + lane];
    float dpa = st[128 + lane], dwt = st[192 + lane];
    float dcg = st[256 + lane], dcc = st[320 + lane];
    float s1 = fmaf(alpha, A1, U1);
    float uwz = fmaf(alpha, fmaf(t, dwt, dpa), fmaf(gma, dcg, dcc));
    float s2 = Qu + 2.0f * alpha * uwz + alpha * alpha * Qz;
    mu1 = s1 * (1.0f / 256.0f);
    inv1 = 1.0f / sqrtf(s2 * (1.0f / 256.0f) - mu1 * mu1 + 1e-5f);
  }
  // ---- per-k affine tables: h1[k][z] = relu(A_k * wz[k][z] + B_k) ----
  {
    int k = tid;
    float ia = inv1 * alpha;
    A_lds[k] = ia * g1_k;
    B_lds[k] = fmaf(inv1, fmaf(-mu1, g1_k, g1_k * u_k), be1[k]);
  }
  __syncthreads();

  // ---- GEMM1: h2[128][64] = W2 @ h1, K=256 in 4 chunks of 64 ----
  f32x4 acc[2][4];
  #pragma unroll
  for (int a = 0; a < 2; ++a)
    #pragma unroll
    for (int b = 0; b < 4; ++b) acc[a][b] = zero4;

  for (int kc = 0; kc < 4; ++kc) {
    if (kc) __syncthreads();          // previous chunk's MFMA readers done
    // producers: 2 octets per wave; h = relu(A*wz+B), packed f32 pairs
    #pragma unroll
    for (int q = 0; q < 2; ++q) {
      int o = w * 2 + q;
      int kb = kc * 64 + o * 8;
      f32x4 A0 = *(const f32x4*)(A_lds + kb);
      f32x4 A1v = *(const f32x4*)(A_lds + kb + 4);
      f32x4 B0 = *(const f32x4*)(B_lds + kb);
      f32x4 B1v = *(const f32x4*)(B_lds + kb + 4);
      u32x4 vh, vl;
      #pragma unroll
      for (int e = 0; e < 4; ++e) {
        int k0 = kb + 2 * e, k1 = kb + 2 * e + 1;
        f32x2 wz2 = pk2(wzT[k0 * 64 + lane], wzT[k1 * 64 + lane]);
        f32x2 A2 = (e < 2) ? pk2(A0[2 * e], A0[2 * e + 1])
                           : pk2(A1v[2 * e - 4], A1v[2 * e - 3]);
        f32x2 B2 = (e < 2) ? pk2(B0[2 * e], B0[2 * e + 1])
                           : pk2(B1v[2 * e - 4], B1v[2 * e - 3]);
        f32x2 h2 = __builtin_elementwise_max(
            __builtin_elementwise_fma(A2, wz2, B2), zero2);
        u2 s = split2v(h2);
        vh[e] = s.hi; vl[e] = s.lo;
      }
      int slotd = (((o >> 2) * 4 + lhi) * 64 + (o & 3) * 16 + l15) * 4;
      *(u32x4*)((unsigned*)Bhi + slotd) = vh;
      *(u32x4*)((unsigned*)Blo + slotd) = vl;
    }
    __syncthreads();
    // MFMA: wave owns M rows [32w, 32w+32)
    #pragma unroll
    for (int kt = 0; kt < 2; ++kt) {
      int ktg = kc * 2 + kt;
      bf16x8 a0h = *(const bf16x8*)(W2Ah + (((2 * w + 0) * 8 + ktg) * 64 + lane) * 8);
      bf16x8 a0l = *(const bf16x8*)(W2Al + (((2 * w + 0) * 8 + ktg) * 64 + lane) * 8);
      bf16x8 a1h = *(const bf16x8*)(W2Ah + (((2 * w + 1) * 8 + ktg) * 64 + lane) * 8);
      bf16x8 a1l = *(const bf16x8*)(W2Al + (((2 * w + 1) * 8 + ktg) * 64 + lane) * 8);
      #pragma unroll
      for (int nt = 0; nt < 4; ++nt) {
        bf16x8 bh = *(const bf16x8*)(Bhi + ((kt * 4 + nt) * 64 + lane) * 8);
        bf16x8 bl = *(const bf16x8*)(Blo + ((kt * 4 + nt) * 64 + lane) * 8);
        acc[0][nt] = MFMA(a0h, bh, acc[0][nt]);
        acc[0][nt] = MFMA(a0h, bl, acc[0][nt]);
        acc[0][nt] = MFMA(a0l, bh, acc[0][nt]);
        acc[1][nt] = MFMA(a1h, bh, acc[1][nt]);
        acc[1][nt] = MFMA(a1h, bl, acc[1][nt]);
        acc[1][nt] = MFMA(a1l, bh, acc[1][nt]);
      }
    }
  }

  // +b2, LN2 partial sums (per column over 128 rows)
  #pragma unroll
  for (int mti = 0; mti < 2; ++mti) {
    f32x4 bv = *(const f32x4*)(b2 + w * 32 + mti * 16 + lhi * 4);
    #pragma unroll
    for (int nt = 0; nt < 4; ++nt) acc[mti][nt] += bv;
  }
  #pragma unroll
  for (int nt = 0; nt < 4; ++nt) {
    float x1 = 0.f, x2 = 0.f;
    #pragma unroll
    for (int mti = 0; mti < 2; ++mti)
      #pragma unroll
      for (int r = 0; r < 4; ++r) { float v = acc[mti][nt][r]; x1 += v; x2 += v * v; }
    x1 += __shfl_xor(x1, 16, 64); x1 += __shfl_xor(x1, 32, 64);
    x2 += __shfl_xor(x2, 16, 64); x2 += __shfl_xor(x2, 32, 64);
    if (lane < 16) {
      ps[w * 64 + nt * 16 + lane] = x1;
      ps[256 + w * 64 + nt * 16 + lane] = x2;
    }
  }
  __syncthreads();
  // P/Q table for LN2 (wave 0 only; one rsqrt per column)
  if (w == 0) {
    int c = lane;
    float a = ps[c] + ps[64 + c] + ps[128 + c] + ps[192 + c];
    float b = ps[256 + c] + ps[320 + c] + ps[384 + c] + ps[448 + c];
    float mu = a * (1.0f / 128.0f);
    float inv = 1.0f / sqrtf(b * (1.0f / 128.0f) - mu * mu + 1e-5f);
    ps[c] = inv;               // P
    ps[64 + c] = -mu * inv;    // Q
  }
  __syncthreads();

  // ---- GEMM2: h3[64][64] = W3 @ h2, K=128 in 2 chunks of 64 ----
  f32x4 acc2[4];
  #pragma unroll
  for (int b = 0; b < 4; ++b) acc2[b] = zero4;

  for (int kc2 = 0; kc2 < 2; ++kc2) {
    if ((w >> 1) == kc2) {            // waves 2*kc2, 2*kc2+1 own these h2 rows
      f32x4 g2v[2], be2v[2];
      #pragma unroll
      for (int mti = 0; mti < 2; ++mti) {
        g2v[mti]  = *(const f32x4*)(g2  + w * 32 + mti * 16 + lhi * 4);
        be2v[mti] = *(const f32x4*)(be2 + w * 32 + mti * 16 + lhi * 4);
      }
      #pragma unroll
      for (int nt = 0; nt < 4; ++nt) {
        int c = nt * 16 + l15;
        float P = ps[c], Q = ps[64 + c];
        f32x2 Pv = pk2(P, P), Qv = pk2(Q, Q);
        #pragma unroll
        for (int mti = 0; mti < 2; ++mti) {
          f32x2 G01 = pk2(g2v[mti][0], g2v[mti][1]);
          f32x2 G23 = pk2(g2v[mti][2], g2v[mti][3]);
          f32x2 be01 = pk2(be2v[mti][0], be2v[mti][1]);
          f32x2 be23 = pk2(be2v[mti][2], be2v[mti][3]);
          f32x2 a01 = pk2(acc[mti][nt][0], acc[mti][nt][1]);
          f32x2 a23 = pk2(acc[mti][nt][2], acc[mti][nt][3]);
          f32x2 h01 = __builtin_elementwise_max(
              __builtin_elementwise_fma(a01, G01 * Pv,
                  __builtin_elementwise_fma(G01, Qv, be01)), zero2);
          f32x2 h23 = __builtin_elementwise_max(
              __builtin_elementwise_fma(a23, G23 * Pv,
                  __builtin_elementwise_fma(G23, Qv, be23)), zero2);
          u2 s01 = split2v(h01);
          u2 s23 = split2v(h23);
          int base = (((w - 2 * kc2) * 4 + nt) * 64 +
                      (mti * 2 + (lhi >> 1)) * 16 + l15) * 8 + (lhi & 1) * 4;
          u32x2 vh = {s01.hi, s23.hi};
          u32x2 vl = {s01.lo, s23.lo};
          *(u32x2*)(Bhi + base) = vh;
          *(u32x2*)(Blo + base) = vl;
        }
      }
    }
    __syncthreads();
    #pragma unroll
    for (int kt = 0; kt < 2; ++kt) {
      int ktg = kc2 * 2 + kt;
      bf16x8 ah = *(const bf16x8*)(W3Ah + ((w * 4 + ktg) * 64 + lane) * 8);
      bf16x8 al = *(const bf16x8*)(W3Al + ((w * 4 + ktg) * 64 + lane) * 8);
      #pragma unroll
      for (int nt = 0; nt < 4; ++nt) {
        bf16x8 bh = *(const bf16x8*)(Bhi + ((kt * 4 + nt) * 64 + lane) * 8);
        bf16x8 bl = *(const bf16x8*)(Blo + ((kt * 4 + nt) * 64 + lane) * 8);
        acc2[nt] = MFMA(ah, bh, acc2[nt]);
        acc2[nt] = MFMA(ah, bl, acc2[nt]);
        acc2[nt] = MFMA(al, bh, acc2[nt]);
      }
    }
    __syncthreads();
  }

  // +b3, LN3 partial sums
  {
    f32x4 bv = *(const f32x4*)(b3 + w * 16 + lhi * 4);
    #pragma unroll
    for (int nt = 0; nt < 4; ++nt) acc2[nt] += bv;
  }
  #pragma unroll
  for (int nt = 0; nt < 4; ++nt) {
    float x1 = 0.f, x2 = 0.f;
    #pragma unroll
    for (int r = 0; r < 4; ++r) { float v = acc2[nt][r]; x1 += v; x2 += v * v; }
    x1 += __shfl_xor(x1, 16, 64); x1 += __shfl_xor(x1, 32, 64);
    x2 += __shfl_xor(x2, 16, 64); x2 += __shfl_xor(x2, 32, 64);
    if (lane < 16) {
      ps[w * 64 + nt * 16 + lane] = x1;
      ps[256 + w * 64 + nt * 16 + lane] = x2;
    }
  }
  __syncthreads();
  if (w == 0) {
    int c = lane;
    float a = ps[c] + ps[64 + c] + ps[128 + c] + ps[192 + c];
    float b = ps[256 + c] + ps[320 + c] + ps[384 + c] + ps[448 + c];
    float mu = a * (1.0f / 64.0f);
    float inv = 1.0f / sqrtf(b * (1.0f / 64.0f) - mu * mu + 1e-5f);
    ps[c] = inv;               // P
    ps[64 + c] = -mu * inv;    // Q
  }
  __syncthreads();

  // ---- B3 producers: all waves, direct scatter from acc2 ----
  {
    f32x4 g3v  = *(const f32x4*)(g3  + w * 16 + lhi * 4);
    f32x4 be3v = *(const f32x4*)(be3 + w * 16 + lhi * 4);
    f32x2 G01 = pk2(g3v[0], g3v[1]), G23 = pk2(g3v[2], g3v[3]);
    f32x2 be01 = pk2(be3v[0], be3v[1]), be23 = pk2(be3v[2], be3v[3]);
    #pragma unroll
    for (int nt = 0; nt < 4; ++nt) {
      int c = nt * 16 + l15;
      float P = ps[c], Q = ps[64 + c];
      f32x2 Pv = pk2(P, P), Qv = pk2(Q, Q);
      f32x2 a01 = pk2(acc2[nt][0], acc2[nt][1]);
      f32x2 a23 = pk2(acc2[nt][2], acc2[nt][3]);
      f32x2 h01 = __builtin_elementwise_max(
          __builtin_elementwise_fma(a01, G01 * Pv,
              __builtin_elementwise_fma(G01, Qv, be01)), zero2);
      f32x2 h23 = __builtin_elementwise_max(
          __builtin_elementwise_fma(a23, G23 * Pv,
              __builtin_elementwise_fma(G23, Qv, be23)), zero2);
      u2 s01 = split2v(h01);
      u2 s23 = split2v(h23);
      int base = (((w >> 1) * 4 + nt) * 64 +
                  ((w & 1) * 2 + (lhi >> 1)) * 16 + l15) * 8 + (lhi & 1) * 4;
      u32x2 vh = {s01.hi, s23.hi};
      u32x2 vl = {s01.lo, s23.lo};
      *(u32x2*)(Bhi + base) = vh;
      *(u32x2*)(Blo + base) = vl;
    }
  }
  __syncthreads();

  // ---- GEMM3: raw[64][64] = W4 @ h3 ----
  f32x4 acc3[4];
  #pragma unroll
  for (int b = 0; b < 4; ++b) acc3[b] = zero4;
  #pragma unroll
  for (int kt = 0; kt < 2; ++kt) {
    bf16x8 ah = *(const bf16x8*)(W4Ah + ((w * 2 + kt) * 64 + lane) * 8);
    bf16x8 al = *(const bf16x8*)(W4Al + ((w * 2 + kt) * 64 + lane) * 8);
    #pragma unroll
    for (int nt = 0; nt < 4; ++nt) {
      bf16x8 bh = *(const bf16x8*)(Bhi + ((kt * 4 + nt) * 64 + lane) * 8);
      bf16x8 bl = *(const bf16x8*)(Blo + ((kt * 4 + nt) * 64 + lane) * 8);
      acc3[nt] = MFMA(ah, bh, acc3[nt]);
      acc3[nt] = MFMA(ah, bl, acc3[nt]);
      acc3[nt] = MFMA(al, bh, acc3[nt]);
    }
  }
  f32x4 b4v = *(const f32x4*)(b4 + w * 16 + lhi * 4);
  unsigned long long kbest[4];
  #pragma unroll
  for (int nt = 0; nt < 4; ++nt) {
    unsigned long long am = adj[nt * 16 + l15];
    unsigned long long kb = 0ull;
    #pragma unroll
    for (int r = 0; r < 4; ++r) {
      int o = w * 16 + lhi * 4 + r;
      float raw = acc3[nt][r] + b4v[r];
      float val = ((am >> o) & 1ull) ? raw : -__builtin_huge_valf();
      unsigned u = __float_as_uint(val);
      u = (u & 0x80000000u) ? ~u : (u | 0x80000000u);
      unsigned long long key = ((unsigned long long)u << 6) | (unsigned long long)(63 - o);
      if (key > kb) kb = key;
    }
    unsigned long long oth = __shfl_xor(kb, 16, 64); if (oth > kb) kb = oth;
    oth = __shfl_xor(kb, 32, 64); if (oth > kb) kb = oth;
    kbest[nt] = kb;
  }
  if (lane < 16) {
    #pragma unroll
    for (int nt = 0; nt < 4; ++nt) pk[w * 64 + nt * 16 + lane] = kbest[nt];
  }
  __syncthreads();
  if (tid < 64) {
    unsigned long long k0 = pk[tid], k1 = pk[64 + tid];
    unsigned long long k2 = pk[128 + tid], k3 = pk[192 + tid];
    unsigned long long a = k0 > k1 ? k0 : k1;
    unsigned long long b = k2 > k3 ? k2 : k3;
    unsigned long long bb = a > b ? a : b;
    nxt[(size_t)i * 64 + tid] = (unsigned char)(63u - (unsigned)(bb & 63ull));
  }
}

// ---------------- trajectory via parallel map-composition scan ----------------

__global__ void k_scan_a(const unsigned char* __restrict__ nxt,
                         unsigned char* __restrict__ cmap) {
  int c = blockIdx.x, lane = threadIdx.x;
  int g = lane;
  const unsigned char* p = nxt + (size_t)c * 128 * 64;
  for (int s = 0; s < 128; ++s) {
    int sig = p[s * 64 + lane];
    g = __shfl(sig, g, 64);
  }
  cmap[c * 64 + lane] = (unsigned char)g;
}

__global__ void k_scan_b(const unsigned char* __restrict__ cmap,
                         int* __restrict__ startz) {
  int lane = threadIdx.x;
  int cur = 0;
  for (int c = 0; c < 256; ++c) {
    if (lane == 0) startz[c] = cur;
    int row = cmap[c * 64 + lane];
    cur = __shfl(row, cur, 64);
  }
}

__global__ void k_scan_c(const unsigned char* __restrict__ nxt,
                         const int* __restrict__ startz,
                         unsigned char* __restrict__ zones) {
  int c = blockIdx.x, lane = threadIdx.x;
  int cur = startz[c];
  const unsigned char* p = nxt + (size_t)c * 128 * 64;
  for (int s = 0; s < 128; ++s) {
    if (lane == 0) zones[c * 128 + s] = (unsigned char)cur;
    int row = p[s * 64 + lane];
    cur = __shfl(row, cur, 64);
  }
}

// ---------------- pass 2m: logits for actual zones, 64 timesteps/block ----------------

__global__ __launch_bounds__(256, 2) void k_pass2m(
    const float* __restrict__ times, const unsigned char* __restrict__ zones,
    const float* __restrict__ c_pa, const float* __restrict__ w_t,
    const float* __restrict__ c_g, const float* __restrict__ c_const,
    const float* __restrict__ wzZ, const float* __restrict__ st,
    const unsigned short* __restrict__ W2Ah, const unsigned short* __restrict__ W2Al,
    const unsigned short* __restrict__ W3Ah, const unsigned short* __restrict__ W3Al,
    const unsigned short* __restrict__ W4Ah, const unsigned short* __restrict__ W4Al,
    const float* __restrict__ b2, const float* __restrict__ b3,
    const float* __restrict__ b4,
    const float* __restrict__ g1, const float* __restrict__ be1,
    const float* __restrict__ g2, const float* __restrict__ be2,
    const float* __restrict__ g3, const float* __restrict__ be3,
    const unsigned long long* __restrict__ adj,
    float* __restrict__ out) {
  __shared__ __align__(16) char region[32768];
  __shared__ float ps1[256], ps2[256];
  __shared__ unsigned long long am_lds[64];

  unsigned short* B1hi = (unsigned short*)region;
  unsigned short* B1lo = (unsigned short*)(region + 16384);
  float* h2p = (float*)region;
  unsigned short* B2hi = (unsigned short*)region;
  unsigned short* B2lo = (unsigned short*)(region + 16384);
  float* h3p = (float*)region;
  unsigned short* B3hi = (unsigned short*)(region + 16384);
  unsigned short* B3lo = (unsigned short*)(region + 24576);
  float* outT = (float*)region;

  const int tid = threadIdx.x;
  const int lane = tid & 63;
  const int l15 = lane & 15;
  const int lhi = lane >> 4;
  const int w = __builtin_amdgcn_readfirstlane(tid >> 6);
  const int i0 = blockIdx.x * 64;

  const float t = times[i0 + lane];
  const int z = zones[i0 + lane];
  const int zrow = z << 8;
  if (tid < 64) am_lds[tid] = adj[zones[i0 + tid]];

  const float m0 = (st[384] + t + 1.0f) * (1.0f / 97.0f);
  const float e2 = (st[385] + t * t + 1.0f) * (1.0f / 97.0f);
  const float a0 = 1.0f / sqrtf(e2 - m0 * m0 + 1e-5f);
  const float a1 = a0 * t;
  const float a2 = -m0 * a0;

  float mu1, inv1;
  {
    float SP = st[386], SW = st[387], SG = st[388], SC = st[389];
    float PP = st[390], PW = st[391], PG = st[392], PC = st[393];
    float WW = st[394], WG = st[395], WC = st[396];
    float GG = st[397], GC = st[398], CC = st[399];
    float U1 = a0 * SP + a1 * SW + a2 * SG + SC;
    float s1 = fmaf(a0, st[z], U1);
    float Qu = a0 * a0 * PP + a1 * a1 * WW + a2 * a2 * GG + CC
             + 2.0f * (a0 * a1 * PW + a0 * a2 * PG + a0 * PC
                       + a1 * a2 * WG + a1 * WC + a2 * GC);
    float uwz = a0 * st[128 + z] + a1 * st[192 + z] + a2 * st[256 + z] + st[320 + z];
    float s2 = Qu + 2.0f * a0 * uwz + a0 * a0 * st[64 + z];
    mu1 = s1 * (1.0f / 256.0f);
    inv1 = 1.0f / sqrtf(s2 * (1.0f / 256.0f) - mu1 * mu1 + 1e-5f);
  }

  const f32x4 zero4 = {0.f, 0.f, 0.f, 0.f};
  f32x4 acc[2][4];
  #pragma unroll
  for (int a = 0; a < 2; ++a)
    #pragma unroll
    for (int b = 0; b < 4; ++b) acc[a][b] = zero4;

  for (int kc = 0; kc < 2; ++kc) {
    if (kc) __syncthreads();
    #pragma unroll
    for (int q = 0; q < 4; ++q) {
      int kb = kc * 128 + w * 32 + q * 8;
      float hbuf[8];
      #pragma unroll
      for (int j = 0; j < 8; ++j) {
        int k = kb + j;
        float u = fmaf(a0, c_pa[k], fmaf(a1, w_t[k], fmaf(a2, c_g[k], c_const[k])));
        float p = fmaf(a0, wzZ[zrow + k], u);
        float gi = g1[k] * inv1;
        float bb = fmaf(-mu1, gi, be1[k]);
        hbuf[j] = fmaxf(fmaf(p, gi, bb), 0.f);
      }
      u32x4 vh, vl;
      #pragma unroll
      for (int e = 0; e < 4; ++e) {
        u2 s = split2(hbuf[2 * e], hbuf[2 * e + 1]);
        vh[e] = s.hi; vl[e] = s.lo;
      }
      int slotd = ((w * 4 + lhi) * 64 + q * 16 + l15) * 4;
      *(u32x4*)((unsigned*)B1hi + slotd) = vh;
      *(u32x4*)((unsigned*)B1lo + slotd) = vl;
    }
    __syncthreads();
    for (int kt = 0; kt < 4; ++kt) {
      int ktg = kc * 4 + kt;
      bf16x8 a0h = *(const bf16x8*)(W2Ah + (((2 * w + 0) * 8 + ktg) * 64 + lane) * 8);
      bf16x8 a0l = *(const bf16x8*)(W2Al + (((2 * w + 0) * 8 + ktg) * 64 + lane) * 8);
      bf16x8 a1h = *(const bf16x8*)(W2Ah + (((2 * w + 1) * 8 + ktg) * 64 + lane) * 8);
      bf16x8 a1l = *(const bf16x8*)(W2Al + (((2 * w + 1) * 8 + ktg) * 64 + lane) * 8);
      #pragma unroll
      for (int nt = 0; nt < 4; ++nt) {
        bf16x8 bh = *(const bf16x8*)(B1hi + ((kt * 4 + nt) * 64 + lane) * 8);
        bf16x8 bl = *(const bf16x8*)(B1lo + ((kt * 4 + nt) * 64 + lane) * 8);
        acc[0][nt] = MFMA(a0h, bh, acc[0][nt]);
        acc[0][nt] = MFMA(a0h, bl, acc[0][nt]);
        acc[0][nt] = MFMA(a0l, bh, acc[0][nt]);
        acc[1][nt] = MFMA(a1h, bh, acc[1][nt]);
        acc[1][nt] = MFMA(a1h, bl, acc[1][nt]);
        acc[1][nt] = MFMA(a1l, bh, acc[1][nt]);
      }
    }
  }
  #pragma unroll
  for (int mti = 0; mti < 2; ++mti) {
    f32x4 bv = *(const f32x4*)(b2 + w * 32 + mti * 16 + lhi * 4);
    #pragma unroll
    for (int nt = 0; nt < 4; ++nt) acc[mti][nt] += bv;
  }
  {
    float sa[4], sb[4];
    #pragma unroll
    for (int nt = 0; nt < 4; ++nt) {
      float x1 = 0.f, x2 = 0.f;
      #pragma unroll
      for (int mti = 0; mti < 2; ++mti)
        #pragma unroll
        for (int r = 0; r < 4; ++r) { float v = acc[mti][nt][r]; x1 += v; x2 += v * v; }
      x1 += __shfl_xor(x1, 16, 64); x1 += __shfl_xor(x1, 32, 64);
      x2 += __shfl_xor(x2, 16, 64); x2 += __shfl_xor(x2, 32, 64);
      sa[nt] = x1; sb[nt] = x2;
    }
    if (lane < 16) {
      #pragma unroll
      for (int nt = 0; nt < 4; ++nt) {
        ps1[w * 64 + nt * 16 + lane] = sa[nt];
        ps2[w * 64 + nt * 16 + lane] = sb[nt];
      }
    }
  }
  __syncthreads();
  #pragma unroll
  for (int mti = 0; mti < 2; ++mti)
    #pragma unroll
    for (int nt = 0; nt < 4; ++nt)
      #pragma unroll
      for (int r = 0; r < 4; ++r) {
        int row = w * 32 + mti * 16 + lhi * 4 + r;
        h2p[row * 64 + SWZ(row, nt * 16 + l15)] = acc[mti][nt][r];
      }
  __syncthreads();

  float mu2, inv2;
  {
    float a = ps1[lane] + ps1[64 + lane] + ps1[128 + lane] + ps1[192 + lane];
    float b = ps2[lane] + ps2[64 + lane] + ps2[128 + lane] + ps2[192 + lane];
    mu2 = a * (1.0f / 128.0f);
    inv2 = 1.0f / sqrtf(b * (1.0f / 128.0f) - mu2 * mu2 + 1e-5f);
  }
  float hv[32];
  #pragma unroll
  for (int mi = 0; mi < 32; ++mi) {
    int row = w * 32 + mi;
    hv[mi] = h2p[row * 64 + SWZ(row, lane)];
  }
  __syncthreads();
  #pragma unroll
  for (int q = 0; q < 4; ++q) {
    float hbuf[8];
    #pragma unroll
    for (int j = 0; j < 8; ++j) {
      int mi = q * 8 + j, mm = w * 32 + mi;
      float gi = g2[mm] * inv2;
      float bb = fmaf(-mu2, gi, be2[mm]);
      hbuf[j] = fmaxf(fmaf(hv[mi], gi, bb), 0.f);
    }
    u32x4 vh, vl;
    #pragma unroll
    for (int e = 0; e < 4; ++e) {
      u2 s = split2(hbuf[2 * e], hbuf[2 * e + 1]);
      vh[e] = s.hi; vl[e] = s.lo;
    }
    int slotd = ((w * 4 + lhi) * 64 + q * 16 + l15) * 4;
    *(u32x4*)((unsigned*)B2hi + slotd) = vh;
    *(u32x4*)((unsigned*)B2lo + slotd) = vl;
  }
  __syncthreads();

  f32x4 acc2[4];
  #pragma unroll
  for (int b = 0; b < 4; ++b) acc2[b] = zero4;
  for (int kt = 0; kt < 4; ++kt) {
    bf16x8 ah = *(const bf16x8*)(W3Ah + ((w * 4 + kt) * 64 + lane) * 8);
    bf16x8 al = *(const bf16x8*)(W3Al + ((w * 4 + kt) * 64 + lane) * 8);
    #pragma unroll
    for (int nt = 0; nt < 4; ++nt) {
      bf16x8 bh = *(const bf16x8*)(B2hi + ((kt * 4 + nt) * 64 + lane) * 8);
      bf16x8 bl = *(const bf16x8*)(B2lo + ((kt * 4 + nt) * 64 + lane) * 8);
      acc2[nt] = MFMA(ah, bh, acc2[nt]);
      acc2[nt] = MFMA(ah, bl, acc2[nt]);
      acc2[nt] = MFMA(al, bh, acc2[nt]);
    }
  }
  {
    f32x4 bv = *(const f32x4*)(b3 + w * 16 + lhi * 4);
    #pragma unroll
    for (int nt = 0; nt < 4; ++nt) acc2[nt] += bv;
  }
  {
    float sa[4], sb[4];
    #pragma unroll
    for (int nt = 0; nt < 4; ++nt) {
      float x1 = 0.f, x2 = 0.f;
      #pragma unroll
      for (int r = 0; r < 4; ++r) { float v = acc2[nt][r]; x1 += v; x2 += v * v; }
      x1 += __shfl_xor(x1, 16, 64); x1 += __shfl_xor(x1, 32, 64);
      x2 += __shfl_xor(x2, 16, 64); x2 += __shfl_xor(x2, 32, 64);
      sa[nt] = x1; sb[nt] = x2;
    }
    if (lane < 16) {
      #pragma unroll
      for (int nt = 0; nt < 4; ++nt) {
        ps1[w * 64 + nt * 16 + lane] = sa[nt];
        ps2[w * 64 + nt * 16 + lane] = sb[nt];
      }
    }
  }
  __syncthreads();
  #pragma unroll
  for (int nt = 0; nt < 4; ++nt)
    #pragma unroll
    for (int r = 0; r < 4; ++r) {
      int row = w * 16 + lhi * 4 + r;
      h3p[row * 64 + SWZ(row, nt * 16 + l15)] = acc2[nt][r];
    }
  __syncthreads();

  float mu3, inv3;
  {
    float a = ps1[lane] + ps1[64 + lane] + ps1[128 + lane] + ps1[192 + lane];
    float b = ps2[lane] + ps2[64 + lane] + ps2[128 + lane] + ps2[192 + lane];
    mu3 = a * (1.0f / 64.0f);
    inv3 = 1.0f / sqrtf(b * (1.0f / 64.0f) - mu3 * mu3 + 1e-5f);
  }
  #pragma unroll
  for (int q = 0; q < 2; ++q) {
    int o = w * 2 + q;
    float hbuf[8];
    #pragma unroll
    for (int j = 0; j < 8; ++j) {
      int mm = o * 8 + j;
      float v = h3p[mm * 64 + SWZ(mm, lane)];
      float gi = g3[mm] * inv3;
      float bb = fmaf(-mu3, gi, be3[mm]);
      hbuf[j] = fmaxf(fmaf(v, gi, bb), 0.f);
    }
    u32x4 vh, vl;
    #pragma unroll
    for (int e = 0; e < 4; ++e) {
      u2 s = split2(hbuf[2 * e], hbuf[2 * e + 1]);
      vh[e] = s.hi; vl[e] = s.lo;
    }
    int slotd = (((o >> 2) * 4 + lhi) * 64 + (o & 3) * 16 + l15) * 4;
    *(u32x4*)((unsigned*)B3hi + slotd) = vh;
    *(u32x4*)((unsigned*)B3lo + slotd) = vl;
  }
  __syncthreads();

  f32x4 acc3[4];
  #pragma unroll
  for (int b = 0; b < 4; ++b) acc3[b] = zero4;
  for (int kt = 0; kt < 2; ++kt) {
    bf16x8 ah = *(const bf16x8*)(W4Ah + ((w * 2 + kt) * 64 + lane) * 8);
    bf16x8 al = *(const bf16x8*)(W4Al + ((w * 2 + kt) * 64 + lane) * 8);
    #pragma unroll
    for (int nt = 0; nt < 4; ++nt) {
      bf16x8 bh = *(const bf16x8*)(B3hi + ((kt * 4 + nt) * 64 + lane) * 8);
      bf16x8 bl = *(const bf16x8*)(B3lo + ((kt * 4 + nt) * 64 + lane) * 8);
      acc3[nt] = MFMA(ah, bh, acc3[nt]);
      acc3[nt] = MFMA(ah, bl, acc3[nt]);
      acc3[nt] = MFMA(al, bh, acc3[nt]);
    }
  }
  f32x4 b4v = *(const f32x4*)(b4 + w * 16 + lhi * 4);
  #pragma unroll
  for (int nt = 0; nt < 4; ++nt) {
    unsigned long long am = am_lds[nt * 16 + l15];
    #pragma unroll
    for (int r = 0; r < 4; ++r) {
      int o = w * 16 + lhi * 4 + r;
      float raw = acc3[nt][r] + b4v[r];
      float predv = ((am >> o) & 1ull) ? raw : -50.0f;
      int b = nt * 16 + l15;
      outT[b * 64 + SWZ(b, o)] = predv;
    }
  }
  __syncthreads();
  {
    int b = tid >> 2, cb = (tid & 3) * 16;
    size_t gbase = ((size_t)(i0 + b)) * 64 + cb;
    #pragma unroll
    for (int c4 = 0; c4 < 4; ++c4) {
      int col = cb + c4 * 4;
      f32x4 v = *(const f32x4*)(outT + b * 64 + SWZ(b, col));
      *(f32x4*)(out + gbase + c4 * 4) = v;
    }
  }
}

// ---------------- launch ----------------

extern "C" void kernel_launch(void* const* d_in, const int* in_sizes, int n_in,
                              void* d_out, int out_size, void* d_ws, size_t ws_size,
                              hipStream_t stream) {
  const float* pa    = (const float*)d_in[0];
  const float* times = (const float*)d_in[1];
  const int*   ei    = (const int*)d_in[3];
  const float* g0    = (const float*)d_in[4];
  const float* b0    = (const float*)d_in[5];
  const float* W1    = (const float*)d_in[6];
  const float* b1    = (const float*)d_in[7];
  const float* g1    = (const float*)d_in[8];
  const float* be1   = (const float*)d_in[9];
  const float* W2    = (const float*)d_in[10];
  const float* b2    = (const float*)d_in[11];
  const float* g2    = (const float*)d_in[12];
  const float* be2   = (const float*)d_in[13];
  const float* W3    = (const float*)d_in[14];
  const float* b3    = (const float*)d_in[15];
  const float* g3    = (const float*)d_in[16];
  const float* be3   = (const float*)d_in[17];
  const float* W4    = (const float*)d_in[18];
  const float* b4    = (const float*)d_in[19];

  char* ws = (char*)d_ws;
  float* c_pa    = (float*)(ws + 0);
  float* w_t     = (float*)(ws + 1024);
  float* c_g     = (float*)(ws + 2048);
  float* c_const = (float*)(ws + 3072);
  unsigned long long* adj = (unsigned long long*)(ws + 4608);
  float* wzT = (float*)(ws + 5120);                       // 64 KB
  float* wzZ = (float*)(ws + 70656);                      // 64 KB
  unsigned short* W2Ah = (unsigned short*)(ws + 136192);  // 64 KB
  unsigned short* W2Al = (unsigned short*)(ws + 201728);  // 64 KB
  unsigned short* W3Ah = (unsigned short*)(ws + 267264);  // 16 KB
  unsigned short* W3Al = (unsigned short*)(ws + 283648);  // 16 KB
  unsigned short* W4Ah = (unsigned short*)(ws + 300032);  // 8 KB
  unsigned short* W4Al = (unsigned short*)(ws + 308224);  // 8 KB
  float* st = (float*)(ws + 316416);                      // 400 floats
  unsigned char* nxt  = (unsigned char*)(ws + 318464);    // 2 MB
  unsigned char* cmap = (unsigned char*)(ws + 2415616);   // 16 KB
  int* startz = (int*)(ws + 2432000);                     // 1 KB
  unsigned char* zones = (unsigned char*)(ws + 2433024);  // 32 KB

  k_setup<<<1, 256, 0, stream>>>(pa, g0, b0, W1, b1, ei, c_pa, w_t, c_g, c_const,
                                 wzT, wzZ, st, adj);
  k_wsplit<<<176, 256, 0, stream>>>(W2, W3, W4, W2Ah, W2Al, W3Ah, W3Al, W4Ah, W4Al);
  k_pass1<<<32768, 256, 0, stream>>>(times, c_pa, w_t, c_g, c_const, wzT, st,
                                     W2Ah, W2Al, W3Ah, W3Al, W4Ah, W4Al,
                                     b2, b3, b4, g1, be1, g2, be2, g3, be3,
                                     adj, nxt);
  k_scan_a<<<256, 64, 0, stream>>>(nxt, cmap);
  k_scan_b<<<1, 64, 0, stream>>>(cmap, startz);
  k_scan_c<<<256, 64, 0, stream>>>(nxt, startz, zones);
  k_pass2m<<<512, 256, 0, stream>>>(times, zones, c_pa, w_t, c_g, c_const,
                                    wzZ, st, W2Ah, W2Al, W3Ah, W3Al, W4Ah, W4Al,
                                    b2, b3, b4, g1, be1, g2, be2, g3, be3,
                                    adj, (float*)d_out);
}